// Round 4
// baseline (515.347 us; speedup 1.0000x reference)
//
#include <hip/hip_runtime.h>
#include <hip/hip_bf16.h>

// Problem constants
// B=4, N=1024, M=4096, DQ=DC=1024, H=16, DH=64, INNER=1024, SCALE=0.125

typedef __attribute__((ext_vector_type(8))) short short8;          // 8 bf16 (MFMA A/B frag)
typedef __attribute__((ext_vector_type(8))) unsigned short u16x8;
typedef __attribute__((ext_vector_type(4))) float f32x4;

static __device__ __forceinline__ void gload_lds16(const void* g, void* l) {
  __builtin_amdgcn_global_load_lds((const __attribute__((address_space(1))) void*)g,
                                   (__attribute__((address_space(3))) void*)l, 16, 0, 0);
}

static __device__ __forceinline__ unsigned short f2bf(float f) {
  __hip_bfloat16 h = __float2bfloat16(f);
  unsigned short u;
  __builtin_memcpy(&u, &h, 2);
  return u;
}

static __device__ __forceinline__ float bf2f(unsigned short u) {
  unsigned int x = (unsigned int)u << 16;
  float f;
  __builtin_memcpy(&f, &x, 4);
  return f;
}

// ---------------- cast fp32 -> bf16, 8 elems/thread ----------------
__global__ __launch_bounds__(256) void cast_bf16_kernel(const float* __restrict__ in,
                                                        unsigned short* __restrict__ out,
                                                        int n8) {
  int idx = blockIdx.x * 256 + threadIdx.x;
  int stride = gridDim.x * 256;
  for (int i = idx; i < n8; i += stride) {
    const float4* p = (const float4*)in + (size_t)i * 2;
    float4 a = p[0], b = p[1];
    u16x8 r;
    r[0] = f2bf(a.x); r[1] = f2bf(a.y); r[2] = f2bf(a.z); r[3] = f2bf(a.w);
    r[4] = f2bf(b.x); r[5] = f2bf(b.y); r[6] = f2bf(b.z); r[7] = f2bf(b.w);
    *((u16x8*)out + i) = r;
  }
}

// ---------------- transpose + cast: W[K][N] fp32 -> Wt[N][K] bf16 ----------------
__global__ __launch_bounds__(256) void transpose_cast_kernel(const float* __restrict__ W,
                                                             unsigned short* __restrict__ Wt,
                                                             int K, int N) {
  __shared__ float tile[32][33];
  int n0 = blockIdx.x * 32, k0 = blockIdx.y * 32;
  int tx = threadIdx.x & 31, ty = threadIdx.x >> 5;
#pragma unroll
  for (int r = 0; r < 32; r += 8)
    tile[ty + r][tx] = W[(size_t)(k0 + ty + r) * N + n0 + tx];
  __syncthreads();
#pragma unroll
  for (int r = 0; r < 32; r += 8)
    Wt[(size_t)(n0 + ty + r) * K + k0 + tx] = f2bf(tile[tx][ty + r]);
}

// ---------------- GEMM: C[M,N] = A[M,K](bf16,row) * Bt[N,K](bf16,row)^T ----------------
// EPI 0: write Q layout [bh][n][64] bf16, PRESCALED by 0.125*log2(e)
// EPI 1: cols<1024 -> K [bh][m][64]; cols>=1024 -> V^T [bh][d][m]
// EPI 2: write fp32 outF[row*1024+col] = acc + bias[col]
template <int EPI>
__global__ __launch_bounds__(256, 2) void gemm_bt_kernel(
    const unsigned short* __restrict__ A, const unsigned short* __restrict__ Bt,
    int M, int N, int K,
    unsigned short* __restrict__ out0, unsigned short* __restrict__ out1,
    float* __restrict__ outF, const float* __restrict__ bias) {
  __shared__ unsigned short As[128 * 64];
  __shared__ unsigned short Bs[128 * 64];
  const int tid = threadIdx.x;
  const int l = tid & 63;
  const int lq = l & 15, g = l >> 4;
  const int w = tid >> 6;
  const int wr = w >> 1, wc = w & 1;
  const int m0 = blockIdx.y * 128, n0 = blockIdx.x * 128;

  f32x4 acc[4][4] = {};

  for (int k0 = 0; k0 < K; k0 += 64) {
    __syncthreads();
#pragma unroll
    for (int t = 0; t < 4; ++t) {
      int c = t * 256 + tid;
      int row = c >> 3, cb = c & 7;
      int srcoff = (cb * 16) ^ ((row & 7) << 4);
      char* la = (char*)As + t * 4096 + (tid & 192) * 16;  // wave-uniform base
      gload_lds16((const char*)(A + (size_t)(m0 + row) * K + k0) + srcoff, la);
      char* lb = (char*)Bs + t * 4096 + (tid & 192) * 16;
      gload_lds16((const char*)(Bt + (size_t)(n0 + row) * K + k0) + srcoff, lb);
    }
    __syncthreads();
#pragma unroll
    for (int ks = 0; ks < 2; ++ks) {
      short8 af[4], bfr[4];
#pragma unroll
      for (int mt = 0; mt < 4; ++mt) {
        int row = wr * 64 + mt * 16 + lq;
        af[mt] = *(const short8*)&As[row * 64 + ((ks * 32 + g * 8) ^ ((row & 7) << 3))];
      }
#pragma unroll
      for (int nt = 0; nt < 4; ++nt) {
        int row = wc * 64 + nt * 16 + lq;
        bfr[nt] = *(const short8*)&Bs[row * 64 + ((ks * 32 + g * 8) ^ ((row & 7) << 3))];
      }
#pragma unroll
      for (int mt = 0; mt < 4; ++mt)
#pragma unroll
        for (int nt = 0; nt < 4; ++nt)
          acc[mt][nt] =
              __builtin_amdgcn_mfma_f32_16x16x32_bf16(af[mt], bfr[nt], acc[mt][nt], 0, 0, 0);
    }
  }

#pragma unroll
  for (int mt = 0; mt < 4; ++mt) {
#pragma unroll
    for (int nt = 0; nt < 4; ++nt) {
      if (EPI == 1 && n0 >= 1024) {
        // V^T: [bh][d][m], 4 m-consecutive values packed per lane
        int colb = n0 - 1024 + wc * 64 + nt * 16 + lq;
        int h = colb >> 6, d = colb & 63;
        int rowb = m0 + wr * 64 + mt * 16 + g * 4;
        int b = rowb >> 12, mm = rowb & 4095;
        ushort4 pk;
        pk.x = f2bf(acc[mt][nt][0]);
        pk.y = f2bf(acc[mt][nt][1]);
        pk.z = f2bf(acc[mt][nt][2]);
        pk.w = f2bf(acc[mt][nt][3]);
        *(ushort4*)&out1[(((size_t)(b * 16 + h)) * 64 + d) * 4096 + mm] = pk;
      } else {
#pragma unroll
        for (int r = 0; r < 4; ++r) {
          int row = m0 + wr * 64 + mt * 16 + g * 4 + r;
          int col = n0 + wc * 64 + nt * 16 + lq;
          float v = acc[mt][nt][r];
          if (EPI == 0) {
            int b = row >> 10, nq = row & 1023;
            int h = col >> 6, d = col & 63;
            // fold softmax scale (0.125 * log2 e) into Q
            out0[(((size_t)(b * 16 + h)) * 1024 + nq) * 64 + d] =
                f2bf(v * 0.18033688011112042f);
          } else if (EPI == 1) {
            int b = row >> 12, mm = row & 4095;
            int h = col >> 6, d = col & 63;
            out0[(((size_t)(b * 16 + h)) * 4096 + mm) * 64 + d] = f2bf(v);
          } else {
            outF[(size_t)row * 1024 + col] = v + bias[col];
          }
        }
      }
    }
  }
}

// ---------------- fused attention (j-split partials) ----------------
// Round-2-verified structure (P through LDS) with: occupancy 4 blocks/CU,
// Q prescaled by 0.125*log2e (at projection), mask folded into the MFMA
// C-operand as 0/-1e30 (clip then yields exactly -5*log2e for masked).
__global__ __launch_bounds__(256, 4) void attn_kernel(
    const unsigned short* __restrict__ Q, const unsigned short* __restrict__ Kb,
    const unsigned short* __restrict__ VbT, const int* __restrict__ mask,
    unsigned short* __restrict__ numP, float* __restrict__ denP) {
  __shared__ unsigned short Ks[64 * 64];      // [j][d], XOR-swizzled content
  __shared__ unsigned short Vt[64 * 64];      // [d][j], XOR-swizzled content
  __shared__ unsigned short Ps[4 * 32 * 64];  // per-wave [q][j], pswz-swizzled

  const int tid = threadIdx.x;
  const int l = tid & 63, w = tid >> 6;
  const int lq = l & 15, g = l >> 4;

  // XCD-affine decode: id&7 = XCD; 8 consecutive same-XCD blocks share (bh,js)
  const int id = blockIdx.x;
  const int xcd = id & 7;
  const int k = id >> 3;
  const int qi = k & 7;
  const int pr = xcd * 32 + (k >> 3);
  const int bh = pr & 63, js = pr >> 6;
  const int b = bh >> 4;
  const int q0 = qi * 128 + w * 32;

  const unsigned short* Qh = Q + (size_t)bh * 1024 * 64;
  const unsigned short* Kh = Kb + (size_t)bh * 4096 * 64;
  const unsigned short* Vth = VbT + (size_t)bh * 64 * 4096;
  const int* mb = mask + b * 4096;

  const float CLIP2 = 7.213475204444817f;  // 5 * log2(e)

  // Q fragments live in registers for the whole kernel (prescaled)
  short8 qf[2][2];
#pragma unroll
  for (int mt = 0; mt < 2; ++mt)
#pragma unroll
    for (int ks = 0; ks < 2; ++ks)
      qf[mt][ks] = *(const short8*)&Qh[(size_t)(q0 + mt * 16 + lq) * 64 + ks * 32 + g * 8];

  f32x4 acc[2][4] = {};
  float denom[2][4] = {};
  unsigned short* Pw = &Ps[w * 2048];

  for (int jt = js * 16; jt < js * 16 + 16; ++jt) {
    const int j0 = jt * 64;
    __syncthreads();  // previous tile fully consumed
    // stage K tile [64 j][64 d] via global_load_lds, source pre-swizzled
#pragma unroll
    for (int t = 0; t < 2; ++t) {
      int c = t * 256 + tid;
      int row = c >> 3, cb = c & 7;
      int srcoff = (cb * 16) ^ ((row & 7) << 4);
      char* lk = (char*)Ks + t * 4096 + (tid & 192) * 16;
      gload_lds16((const char*)(Kh + (size_t)(j0 + row) * 64) + srcoff, lk);
    }
    // stage V^T tile [64 d][64 j] via global_load_lds from precomputed V^T
#pragma unroll
    for (int t = 0; t < 2; ++t) {
      int c = t * 256 + tid;
      int row = c >> 3, cb = c & 7;  // row = d
      int srcoff = (cb * 16) ^ ((row & 7) << 4);
      char* lv = (char*)Vt + t * 4096 + (tid & 192) * 16;
      gload_lds16((const char*)(Vth + (size_t)row * 4096 + j0) + srcoff, lv);
    }
    // per-lane mask bias for its j columns (MFMA C-operand seed)
    float mbias[4];
#pragma unroll
    for (int nt = 0; nt < 4; ++nt) mbias[nt] = mb[j0 + nt * 16 + lq] ? 0.0f : -1e30f;
    __syncthreads();

    // K fragments
    short8 kf[4][2];
#pragma unroll
    for (int nt = 0; nt < 4; ++nt) {
      int row = nt * 16 + lq;
#pragma unroll
      for (int ks = 0; ks < 2; ++ks)
        kf[nt][ks] = *(const short8*)&Ks[row * 64 + ((ks * 32 + g * 8) ^ ((row & 7) << 3))];
    }

    float tmp[2][4] = {};
#pragma unroll
    for (int mt = 0; mt < 2; ++mt) {
#pragma unroll
      for (int nt = 0; nt < 4; ++nt) {
        f32x4 s = {mbias[nt], mbias[nt], mbias[nt], mbias[nt]};
        s = __builtin_amdgcn_mfma_f32_16x16x32_bf16(qf[mt][0], kf[nt][0], s, 0, 0, 0);
        s = __builtin_amdgcn_mfma_f32_16x16x32_bf16(qf[mt][1], kf[nt][1], s, 0, 0, 0);
#pragma unroll
        for (int r = 0; r < 4; ++r) {
          float v = fminf(fmaxf(s[r], -CLIP2), CLIP2);  // masked -> exactly -CLIP2
          float pE = exp2f(v);
          tmp[mt][r] += pE;
          int q = mt * 16 + g * 4 + r;
          int j = nt * 16 + lq;
          int psw = (((q >> 2) & 3) << 4) ^ ((q & 7) << 3);
          Pw[q * 64 + (j ^ psw)] = f2bf(pE);
        }
      }
    }
    // denominator: reduce over the 16-lane j-group
#pragma unroll
    for (int mt = 0; mt < 2; ++mt)
#pragma unroll
      for (int r = 0; r < 4; ++r) {
        float v = tmp[mt][r];
        v += __shfl_xor(v, 1);
        v += __shfl_xor(v, 2);
        v += __shfl_xor(v, 4);
        v += __shfl_xor(v, 8);
        denom[mt][r] += v;
      }

    // PV
    short8 pa[2][2], vbf[4][2];
#pragma unroll
    for (int mt = 0; mt < 2; ++mt) {
      int row = mt * 16 + lq;
      int psw = (((row >> 2) & 3) << 4) ^ ((row & 7) << 3);
#pragma unroll
      for (int ks = 0; ks < 2; ++ks)
        pa[mt][ks] = *(const short8*)&Pw[row * 64 + ((ks * 32 + g * 8) ^ psw)];
    }
#pragma unroll
    for (int dt = 0; dt < 4; ++dt) {
      int row = dt * 16 + lq;
#pragma unroll
      for (int ks = 0; ks < 2; ++ks)
        vbf[dt][ks] = *(const short8*)&Vt[row * 64 + ((ks * 32 + g * 8) ^ ((row & 7) << 3))];
    }
#pragma unroll
    for (int mt = 0; mt < 2; ++mt)
#pragma unroll
      for (int dt = 0; dt < 4; ++dt) {
        acc[mt][dt] = __builtin_amdgcn_mfma_f32_16x16x32_bf16(pa[mt][0], vbf[dt][0], acc[mt][dt], 0, 0, 0);
        acc[mt][dt] = __builtin_amdgcn_mfma_f32_16x16x32_bf16(pa[mt][1], vbf[dt][1], acc[mt][dt], 0, 0, 0);
      }
  }

  // write partial numerator (bf16) and denominator (fp32)
#pragma unroll
  for (int mt = 0; mt < 2; ++mt)
#pragma unroll
    for (int dt = 0; dt < 4; ++dt)
#pragma unroll
      for (int r = 0; r < 4; ++r) {
        int q = q0 + mt * 16 + g * 4 + r;
        int d = dt * 16 + lq;
        numP[((((size_t)js * 64 + bh) * 1024 + q) * 64) + d] = f2bf(acc[mt][dt][r]);
      }
  if (lq == 0) {
#pragma unroll
    for (int mt = 0; mt < 2; ++mt)
#pragma unroll
      for (int r = 0; r < 4; ++r) {
        int q = q0 + mt * 16 + g * 4 + r;
        denP[(((size_t)js * 64 + bh) * 1024) + q] = denom[mt][r];
      }
  }
}

// ---------------- combine j-split partials, divide, write Ob ----------------
__global__ __launch_bounds__(256) void attn_reduce_kernel(
    const unsigned short* __restrict__ numP, const float* __restrict__ denP,
    unsigned short* __restrict__ Ob) {
  int id = blockIdx.x * 256 + threadIdx.x;  // 0 .. 524287
  int d8 = id & 7;
  int q = (id >> 3) & 1023;
  int bh = id >> 13;
  int b = bh >> 4, h = bh & 15;
  float den = 0.f;
  float o[8] = {0.f, 0.f, 0.f, 0.f, 0.f, 0.f, 0.f, 0.f};
#pragma unroll
  for (int s = 0; s < 4; ++s) {
    const unsigned short* np =
        numP + ((((size_t)s * 64 + bh) * 1024 + q) * 64 + d8 * 8);
    u16x8 v = *(const u16x8*)np;
    den += denP[((size_t)s * 64 + bh) * 1024 + q];
#pragma unroll
    for (int e = 0; e < 8; ++e) o[e] += bf2f(v[e]);
  }
  float r = 1.0f / den;
  u16x8 outv;
#pragma unroll
  for (int e = 0; e < 8; ++e) outv[e] = f2bf(o[e] * r);
  *(u16x8*)&Ob[(((size_t)b * 1024 + q) * 1024) + h * 64 + d8 * 8] = outv;
}

// ---------------- launcher ----------------
extern "C" void kernel_launch(void* const* d_in, const int* in_sizes, int n_in,
                              void* d_out, int out_size, void* d_ws, size_t ws_size,
                              hipStream_t stream) {
  (void)in_sizes; (void)n_in; (void)out_size; (void)ws_size;
  const float* x    = (const float*)d_in[0];
  const float* ctx  = (const float*)d_in[1];
  const int*   mask = (const int*)d_in[2];
  const float* Wq   = (const float*)d_in[3];
  const float* Wkv  = (const float*)d_in[4];
  const float* Wo   = (const float*)d_in[5];
  const float* bo   = (const float*)d_in[6];
  float* out = (float*)d_out;

  char* ws = (char*)d_ws;
  const size_t MB = 1 << 20;
  // 0..40 MiB region is time-shared: {xb, cb} before attention, {numP, denP} after
  unsigned short* numP = (unsigned short*)(ws + 0);        // 32 MiB : [4][64][1024][64] bf16
  float*          denP = (float*)(ws + 32 * MB);           // 1 MiB  : [4][64][1024] fp32
  unsigned short* xb   = (unsigned short*)(ws + 0);        // 8 MiB  : x bf16 [4096][1024]
  unsigned short* cb   = (unsigned short*)(ws + 8 * MB);   // 32 MiB : ctx bf16 [16384][1024]
  unsigned short* WqT  = (unsigned short*)(ws + 40 * MB);  // 2 MiB
  unsigned short* WkvT = (unsigned short*)(ws + 42 * MB);  // 4 MiB
  unsigned short* WoT  = (unsigned short*)(ws + 46 * MB);  // 2 MiB
  unsigned short* Qb   = (unsigned short*)(ws + 48 * MB);  // 8 MiB  : [bh][1024][64] (prescaled)
  unsigned short* Kb   = (unsigned short*)(ws + 56 * MB);  // 32 MiB : [bh][4096][64]
  unsigned short* VbT  = (unsigned short*)(ws + 88 * MB);  // 32 MiB : [bh][64][4096]
  unsigned short* Ob   = (unsigned short*)(ws + 120 * MB); // 8 MiB  : [b][n][1024]

  cast_bf16_kernel<<<2048, 256, 0, stream>>>(x, xb, (4 * 1024 * 1024) / 8);
  cast_bf16_kernel<<<2048, 256, 0, stream>>>(ctx, cb, (16 * 1024 * 1024) / 8);
  transpose_cast_kernel<<<dim3(32, 32), 256, 0, stream>>>(Wq, WqT, 1024, 1024);
  transpose_cast_kernel<<<dim3(64, 32), 256, 0, stream>>>(Wkv, WkvT, 1024, 2048);
  transpose_cast_kernel<<<dim3(32, 32), 256, 0, stream>>>(Wo, WoT, 1024, 1024);

  gemm_bt_kernel<0><<<dim3(8, 32), 256, 0, stream>>>(xb, WqT, 4096, 1024, 1024,
                                                     Qb, (unsigned short*)nullptr,
                                                     (float*)nullptr, (const float*)nullptr);
  gemm_bt_kernel<1><<<dim3(16, 128), 256, 0, stream>>>(cb, WkvT, 16384, 2048, 1024,
                                                       Kb, VbT,
                                                       (float*)nullptr, (const float*)nullptr);
  attn_kernel<<<2048, 256, 0, stream>>>(Qb, Kb, VbT, mask, numP, denP);
  attn_reduce_kernel<<<2048, 256, 0, stream>>>(numP, denP, Ob);
  gemm_bt_kernel<2><<<dim3(8, 32), 256, 0, stream>>>(Ob, WoT, 4096, 1024, 1024,
                                                     (unsigned short*)nullptr, (unsigned short*)nullptr,
                                                     out, bo);
}

// Round 5
// 329.093 us; speedup vs baseline: 1.5660x; 1.5660x over previous
//
#include <hip/hip_runtime.h>
#include <hip/hip_bf16.h>

// Problem constants
// B=4, N=1024, M=4096, DQ=DC=1024, H=16, DH=64, INNER=1024, SCALE=0.125

typedef __attribute__((ext_vector_type(8))) short short8;          // 8 bf16 (MFMA A/B frag)
typedef __attribute__((ext_vector_type(8))) unsigned short u16x8;
typedef __attribute__((ext_vector_type(4))) float f32x4;

static __device__ __forceinline__ void gload_lds16(const void* g, void* l) {
  __builtin_amdgcn_global_load_lds((const __attribute__((address_space(1))) void*)g,
                                   (__attribute__((address_space(3))) void*)l, 16, 0, 0);
}

static __device__ __forceinline__ unsigned short f2bf(float f) {
  __hip_bfloat16 h = __float2bfloat16(f);
  unsigned short u;
  __builtin_memcpy(&u, &h, 2);
  return u;
}

static __device__ __forceinline__ float bf2f(unsigned short u) {
  unsigned int x = (unsigned int)u << 16;
  float f;
  __builtin_memcpy(&f, &x, 4);
  return f;
}

// ---------------- cast fp32 -> bf16, 8 elems/thread ----------------
__global__ __launch_bounds__(256) void cast_bf16_kernel(const float* __restrict__ in,
                                                        unsigned short* __restrict__ out,
                                                        int n8) {
  int idx = blockIdx.x * 256 + threadIdx.x;
  int stride = gridDim.x * 256;
  for (int i = idx; i < n8; i += stride) {
    const float4* p = (const float4*)in + (size_t)i * 2;
    float4 a = p[0], b = p[1];
    u16x8 r;
    r[0] = f2bf(a.x); r[1] = f2bf(a.y); r[2] = f2bf(a.z); r[3] = f2bf(a.w);
    r[4] = f2bf(b.x); r[5] = f2bf(b.y); r[6] = f2bf(b.z); r[7] = f2bf(b.w);
    *((u16x8*)out + i) = r;
  }
}

// ---------------- transpose + cast: W[K][N] fp32 -> Wt[N][K] bf16 ----------------
__global__ __launch_bounds__(256) void transpose_cast_kernel(const float* __restrict__ W,
                                                             unsigned short* __restrict__ Wt,
                                                             int K, int N) {
  __shared__ float tile[32][33];
  int n0 = blockIdx.x * 32, k0 = blockIdx.y * 32;
  int tx = threadIdx.x & 31, ty = threadIdx.x >> 5;
#pragma unroll
  for (int r = 0; r < 32; r += 8)
    tile[ty + r][tx] = W[(size_t)(k0 + ty + r) * N + n0 + tx];
  __syncthreads();
#pragma unroll
  for (int r = 0; r < 32; r += 8)
    Wt[(size_t)(n0 + ty + r) * K + k0 + tx] = f2bf(tile[tx][ty + r]);
}

// ---------------- GEMM: C[M,N] = A[M,K](bf16,row) * Bt[N,K](bf16,row)^T ----------------
// EPI 0: write Q layout [bh][n][64] bf16, PRESCALED by 0.125*log2(e)
// EPI 1: cols<1024 -> K [bh][m][64]; cols>=1024 -> V^T [bh][d][m]
// EPI 2: write fp32 outF[row*1024+col] = acc + bias[col]
template <int EPI>
__global__ __launch_bounds__(256, 2) void gemm_bt_kernel(
    const unsigned short* __restrict__ A, const unsigned short* __restrict__ Bt,
    int M, int N, int K,
    unsigned short* __restrict__ out0, unsigned short* __restrict__ out1,
    float* __restrict__ outF, const float* __restrict__ bias) {
  __shared__ unsigned short As[128 * 64];
  __shared__ unsigned short Bs[128 * 64];
  const int tid = threadIdx.x;
  const int l = tid & 63;
  const int lq = l & 15, g = l >> 4;
  const int w = tid >> 6;
  const int wr = w >> 1, wc = w & 1;
  const int m0 = blockIdx.y * 128, n0 = blockIdx.x * 128;

  f32x4 acc[4][4] = {};

  for (int k0 = 0; k0 < K; k0 += 64) {
    __syncthreads();
#pragma unroll
    for (int t = 0; t < 4; ++t) {
      int c = t * 256 + tid;
      int row = c >> 3, cb = c & 7;
      int srcoff = (cb * 16) ^ ((row & 7) << 4);
      char* la = (char*)As + t * 4096 + (tid & 192) * 16;  // wave-uniform base
      gload_lds16((const char*)(A + (size_t)(m0 + row) * K + k0) + srcoff, la);
      char* lb = (char*)Bs + t * 4096 + (tid & 192) * 16;
      gload_lds16((const char*)(Bt + (size_t)(n0 + row) * K + k0) + srcoff, lb);
    }
    __syncthreads();
#pragma unroll
    for (int ks = 0; ks < 2; ++ks) {
      short8 af[4], bfr[4];
#pragma unroll
      for (int mt = 0; mt < 4; ++mt) {
        int row = wr * 64 + mt * 16 + lq;
        af[mt] = *(const short8*)&As[row * 64 + ((ks * 32 + g * 8) ^ ((row & 7) << 3))];
      }
#pragma unroll
      for (int nt = 0; nt < 4; ++nt) {
        int row = wc * 64 + nt * 16 + lq;
        bfr[nt] = *(const short8*)&Bs[row * 64 + ((ks * 32 + g * 8) ^ ((row & 7) << 3))];
      }
#pragma unroll
      for (int mt = 0; mt < 4; ++mt)
#pragma unroll
        for (int nt = 0; nt < 4; ++nt)
          acc[mt][nt] =
              __builtin_amdgcn_mfma_f32_16x16x32_bf16(af[mt], bfr[nt], acc[mt][nt], 0, 0, 0);
    }
  }

#pragma unroll
  for (int mt = 0; mt < 4; ++mt) {
#pragma unroll
    for (int nt = 0; nt < 4; ++nt) {
      if (EPI == 1 && n0 >= 1024) {
        // V^T: [bh][d][m], 4 m-consecutive values packed per lane
        int colb = n0 - 1024 + wc * 64 + nt * 16 + lq;
        int h = colb >> 6, d = colb & 63;
        int rowb = m0 + wr * 64 + mt * 16 + g * 4;
        int b = rowb >> 12, mm = rowb & 4095;
        ushort4 pk;
        pk.x = f2bf(acc[mt][nt][0]);
        pk.y = f2bf(acc[mt][nt][1]);
        pk.z = f2bf(acc[mt][nt][2]);
        pk.w = f2bf(acc[mt][nt][3]);
        *(ushort4*)&out1[(((size_t)(b * 16 + h)) * 64 + d) * 4096 + mm] = pk;
      } else {
#pragma unroll
        for (int r = 0; r < 4; ++r) {
          int row = m0 + wr * 64 + mt * 16 + g * 4 + r;
          int col = n0 + wc * 64 + nt * 16 + lq;
          float v = acc[mt][nt][r];
          if (EPI == 0) {
            int b = row >> 10, nq = row & 1023;
            int h = col >> 6, d = col & 63;
            // fold softmax scale (0.125 * log2 e) into Q
            out0[(((size_t)(b * 16 + h)) * 1024 + nq) * 64 + d] =
                f2bf(v * 0.18033688011112042f);
          } else if (EPI == 1) {
            int b = row >> 12, mm = row & 4095;
            int h = col >> 6, d = col & 63;
            out0[(((size_t)(b * 16 + h)) * 4096 + mm) * 64 + d] = f2bf(v);
          } else {
            outF[(size_t)row * 1024 + col] = v + bias[col];
          }
        }
      }
    }
  }
}

// ---------------- fused attention (j-split partials, double-buffered) ----------------
// Round-2-verified data path. 2 blocks/CU (L2 chunk sharing: 64 blocks/XCD =
// 8 chunks x 256 KB = 2 MB < 4 MB L2 -- 4/CU thrashed, round 4). K/V staging
// double-buffered: stage tile t+1 during compute of tile t, ONE barrier/tile.
// Q prescaled by 0.125*log2e; mask folded into MFMA C-operand (0/-1e30), clip
// then yields exactly -5*log2e for masked lanes.
__global__ __launch_bounds__(256, 2) void attn_kernel(
    const unsigned short* __restrict__ Q, const unsigned short* __restrict__ Kb,
    const unsigned short* __restrict__ VbT, const int* __restrict__ mask,
    unsigned short* __restrict__ numP, float* __restrict__ denP) {
  __shared__ unsigned short Ks[2][64 * 64];   // [j][d], XOR-swizzled content
  __shared__ unsigned short Vt[2][64 * 64];   // [d][j], XOR-swizzled content
  __shared__ unsigned short Ps[4 * 32 * 64];  // per-wave [q][j], pswz-swizzled

  const int tid = threadIdx.x;
  const int l = tid & 63, w = tid >> 6;
  const int lq = l & 15, g = l >> 4;

  // XCD-affine decode: id&7 = XCD; 8 consecutive same-XCD blocks share (bh,js)
  const int id = blockIdx.x;
  const int xcd = id & 7;
  const int k = id >> 3;
  const int qi = k & 7;
  const int pr = xcd * 32 + (k >> 3);
  const int bh = pr & 63, js = pr >> 6;
  const int b = bh >> 4;
  const int q0 = qi * 128 + w * 32;

  const unsigned short* Qh = Q + (size_t)bh * 1024 * 64;
  const unsigned short* Kh = Kb + (size_t)bh * 4096 * 64;
  const unsigned short* Vth = VbT + (size_t)bh * 64 * 4096;
  const int* mb = mask + b * 4096;

  const float CLIP2 = 7.213475204444817f;  // 5 * log2(e)

  // Q fragments live in registers for the whole kernel (prescaled)
  short8 qf[2][2];
#pragma unroll
  for (int mt = 0; mt < 2; ++mt)
#pragma unroll
    for (int ks = 0; ks < 2; ++ks)
      qf[mt][ks] = *(const short8*)&Qh[(size_t)(q0 + mt * 16 + lq) * 64 + ks * 32 + g * 8];

  f32x4 acc[2][4] = {};
  float denom[2][4] = {};
  unsigned short* Pw = &Ps[w * 2048];

  const int jbeg = js * 16, jend = jbeg + 16;

#define STAGE_KV(jt_, bi_)                                                        \
  do {                                                                            \
    const int j0_ = (jt_)*64;                                                     \
    _Pragma("unroll") for (int t = 0; t < 2; ++t) {                               \
      int c = t * 256 + tid;                                                      \
      int row = c >> 3, cb = c & 7;                                               \
      int srcoff = (cb * 16) ^ ((row & 7) << 4);                                  \
      char* lk = (char*)(&Ks[bi_][0]) + t * 4096 + (tid & 192) * 16;              \
      gload_lds16((const char*)(Kh + (size_t)(j0_ + row) * 64) + srcoff, lk);     \
      char* lv = (char*)(&Vt[bi_][0]) + t * 4096 + (tid & 192) * 16;              \
      gload_lds16((const char*)(Vth + (size_t)row * 4096 + j0_) + srcoff, lv);    \
    }                                                                             \
  } while (0)

  // prologue: stage first tile + its mask bias
  float mb0, mb1, mb2, mb3;
  STAGE_KV(jbeg, 0);
  {
    const int j0 = jbeg * 64;
    mb0 = mb[j0 + 0 + lq] ? 0.0f : -1e30f;
    mb1 = mb[j0 + 16 + lq] ? 0.0f : -1e30f;
    mb2 = mb[j0 + 32 + lq] ? 0.0f : -1e30f;
    mb3 = mb[j0 + 48 + lq] ? 0.0f : -1e30f;
  }
  __syncthreads();  // vmcnt(0) drain: buf0 ready

  int cur = 0;
  for (int jt = jbeg; jt < jend; ++jt) {
    // issue next tile's staging into the other buffer (overlaps compute below)
    float nb0 = 0.f, nb1 = 0.f, nb2 = 0.f, nb3 = 0.f;
    if (jt + 1 < jend) {
      STAGE_KV(jt + 1, cur ^ 1);
      const int j0n = (jt + 1) * 64;
      nb0 = mb[j0n + 0 + lq] ? 0.0f : -1e30f;
      nb1 = mb[j0n + 16 + lq] ? 0.0f : -1e30f;
      nb2 = mb[j0n + 32 + lq] ? 0.0f : -1e30f;
      nb3 = mb[j0n + 48 + lq] ? 0.0f : -1e30f;
    }
    const unsigned short* Kcur = &Ks[cur][0];
    const unsigned short* Vcur = &Vt[cur][0];
    const float mbias[4] = {mb0, mb1, mb2, mb3};  // indexed by unrolled nt only

    // K fragments
    short8 kf[4][2];
#pragma unroll
    for (int nt = 0; nt < 4; ++nt) {
      int row = nt * 16 + lq;
#pragma unroll
      for (int ks = 0; ks < 2; ++ks)
        kf[nt][ks] = *(const short8*)&Kcur[row * 64 + ((ks * 32 + g * 8) ^ ((row & 7) << 3))];
    }

    float tmp[2][4] = {};
#pragma unroll
    for (int mt = 0; mt < 2; ++mt) {
#pragma unroll
      for (int nt = 0; nt < 4; ++nt) {
        f32x4 s = {mbias[nt], mbias[nt], mbias[nt], mbias[nt]};
        s = __builtin_amdgcn_mfma_f32_16x16x32_bf16(qf[mt][0], kf[nt][0], s, 0, 0, 0);
        s = __builtin_amdgcn_mfma_f32_16x16x32_bf16(qf[mt][1], kf[nt][1], s, 0, 0, 0);
#pragma unroll
        for (int r = 0; r < 4; ++r) {
          float v = fminf(fmaxf(s[r], -CLIP2), CLIP2);  // masked -> exactly -CLIP2
          float pE = exp2f(v);
          tmp[mt][r] += pE;
          int q = mt * 16 + g * 4 + r;
          int j = nt * 16 + lq;
          int psw = (((q >> 2) & 3) << 4) ^ ((q & 7) << 3);
          Pw[q * 64 + (j ^ psw)] = f2bf(pE);
        }
      }
    }
    // denominator: reduce over the 16-lane j-group
#pragma unroll
    for (int mt = 0; mt < 2; ++mt)
#pragma unroll
      for (int r = 0; r < 4; ++r) {
        float v = tmp[mt][r];
        v += __shfl_xor(v, 1);
        v += __shfl_xor(v, 2);
        v += __shfl_xor(v, 4);
        v += __shfl_xor(v, 8);
        denom[mt][r] += v;
      }

    // PV
    short8 pa[2][2], vbf[4][2];
#pragma unroll
    for (int mt = 0; mt < 2; ++mt) {
      int row = mt * 16 + lq;
      int psw = (((row >> 2) & 3) << 4) ^ ((row & 7) << 3);
#pragma unroll
      for (int ks = 0; ks < 2; ++ks)
        pa[mt][ks] = *(const short8*)&Pw[row * 64 + ((ks * 32 + g * 8) ^ psw)];
    }
#pragma unroll
    for (int dt = 0; dt < 4; ++dt) {
      int row = dt * 16 + lq;
#pragma unroll
      for (int ks = 0; ks < 2; ++ks)
        vbf[dt][ks] = *(const short8*)&Vcur[row * 64 + ((ks * 32 + g * 8) ^ ((row & 7) << 3))];
    }
#pragma unroll
    for (int mt = 0; mt < 2; ++mt)
#pragma unroll
      for (int dt = 0; dt < 4; ++dt) {
        acc[mt][dt] = __builtin_amdgcn_mfma_f32_16x16x32_bf16(pa[mt][0], vbf[dt][0], acc[mt][dt], 0, 0, 0);
        acc[mt][dt] = __builtin_amdgcn_mfma_f32_16x16x32_bf16(pa[mt][1], vbf[dt][1], acc[mt][dt], 0, 0, 0);
      }

    // single barrier per tile: drains next-tile staging (vmcnt0) and protects
    // buf[cur] from being overwritten before all waves finished reading it
    __syncthreads();
    cur ^= 1;
    mb0 = nb0; mb1 = nb1; mb2 = nb2; mb3 = nb3;
  }
#undef STAGE_KV

  // write partial numerator (bf16) and denominator (fp32)
#pragma unroll
  for (int mt = 0; mt < 2; ++mt)
#pragma unroll
    for (int dt = 0; dt < 4; ++dt)
#pragma unroll
      for (int r = 0; r < 4; ++r) {
        int q = q0 + mt * 16 + g * 4 + r;
        int d = dt * 16 + lq;
        numP[((((size_t)js * 64 + bh) * 1024 + q) * 64) + d] = f2bf(acc[mt][dt][r]);
      }
  if (lq == 0) {
#pragma unroll
    for (int mt = 0; mt < 2; ++mt)
#pragma unroll
      for (int r = 0; r < 4; ++r) {
        int q = q0 + mt * 16 + g * 4 + r;
        denP[(((size_t)js * 64 + bh) * 1024) + q] = denom[mt][r];
      }
  }
}

// ---------------- combine j-split partials, divide, write Ob ----------------
__global__ __launch_bounds__(256) void attn_reduce_kernel(
    const unsigned short* __restrict__ numP, const float* __restrict__ denP,
    unsigned short* __restrict__ Ob) {
  int id = blockIdx.x * 256 + threadIdx.x;  // 0 .. 524287
  int d8 = id & 7;
  int q = (id >> 3) & 1023;
  int bh = id >> 13;
  int b = bh >> 4, h = bh & 15;
  float den = 0.f;
  float o[8] = {0.f, 0.f, 0.f, 0.f, 0.f, 0.f, 0.f, 0.f};
#pragma unroll
  for (int s = 0; s < 4; ++s) {
    const unsigned short* np =
        numP + ((((size_t)s * 64 + bh) * 1024 + q) * 64 + d8 * 8);
    u16x8 v = *(const u16x8*)np;
    den += denP[((size_t)s * 64 + bh) * 1024 + q];
#pragma unroll
    for (int e = 0; e < 8; ++e) o[e] += bf2f(v[e]);
  }
  float r = 1.0f / den;
  u16x8 outv;
#pragma unroll
  for (int e = 0; e < 8; ++e) outv[e] = f2bf(o[e] * r);
  *(u16x8*)&Ob[(((size_t)b * 1024 + q) * 1024) + h * 64 + d8 * 8] = outv;
}

// ---------------- launcher ----------------
extern "C" void kernel_launch(void* const* d_in, const int* in_sizes, int n_in,
                              void* d_out, int out_size, void* d_ws, size_t ws_size,
                              hipStream_t stream) {
  (void)in_sizes; (void)n_in; (void)out_size; (void)ws_size;
  const float* x    = (const float*)d_in[0];
  const float* ctx  = (const float*)d_in[1];
  const int*   mask = (const int*)d_in[2];
  const float* Wq   = (const float*)d_in[3];
  const float* Wkv  = (const float*)d_in[4];
  const float* Wo   = (const float*)d_in[5];
  const float* bo   = (const float*)d_in[6];
  float* out = (float*)d_out;

  char* ws = (char*)d_ws;
  const size_t MB = 1 << 20;
  // 0..40 MiB region is time-shared: {xb, cb} before attention, {numP, denP} after
  unsigned short* numP = (unsigned short*)(ws + 0);        // 32 MiB : [4][64][1024][64] bf16
  float*          denP = (float*)(ws + 32 * MB);           // 1 MiB  : [4][64][1024] fp32
  unsigned short* xb   = (unsigned short*)(ws + 0);        // 8 MiB  : x bf16 [4096][1024]
  unsigned short* cb   = (unsigned short*)(ws + 8 * MB);   // 32 MiB : ctx bf16 [16384][1024]
  unsigned short* WqT  = (unsigned short*)(ws + 40 * MB);  // 2 MiB
  unsigned short* WkvT = (unsigned short*)(ws + 42 * MB);  // 4 MiB
  unsigned short* WoT  = (unsigned short*)(ws + 46 * MB);  // 2 MiB
  unsigned short* Qb   = (unsigned short*)(ws + 48 * MB);  // 8 MiB  : [bh][1024][64] (prescaled)
  unsigned short* Kb   = (unsigned short*)(ws + 56 * MB);  // 32 MiB : [bh][4096][64]
  unsigned short* VbT  = (unsigned short*)(ws + 88 * MB);  // 32 MiB : [bh][64][4096]
  unsigned short* Ob   = (unsigned short*)(ws + 120 * MB); // 8 MiB  : [b][n][1024]

  cast_bf16_kernel<<<2048, 256, 0, stream>>>(x, xb, (4 * 1024 * 1024) / 8);
  cast_bf16_kernel<<<2048, 256, 0, stream>>>(ctx, cb, (16 * 1024 * 1024) / 8);
  transpose_cast_kernel<<<dim3(32, 32), 256, 0, stream>>>(Wq, WqT, 1024, 1024);
  transpose_cast_kernel<<<dim3(64, 32), 256, 0, stream>>>(Wkv, WkvT, 1024, 2048);
  transpose_cast_kernel<<<dim3(32, 32), 256, 0, stream>>>(Wo, WoT, 1024, 1024);

  gemm_bt_kernel<0><<<dim3(8, 32), 256, 0, stream>>>(xb, WqT, 4096, 1024, 1024,
                                                     Qb, (unsigned short*)nullptr,
                                                     (float*)nullptr, (const float*)nullptr);
  gemm_bt_kernel<1><<<dim3(16, 128), 256, 0, stream>>>(cb, WkvT, 16384, 2048, 1024,
                                                       Kb, VbT,
                                                       (float*)nullptr, (const float*)nullptr);
  attn_kernel<<<2048, 256, 0, stream>>>(Qb, Kb, VbT, mask, numP, denP);
  attn_reduce_kernel<<<2048, 256, 0, stream>>>(numP, denP, Ob);
  gemm_bt_kernel<2><<<dim3(8, 32), 256, 0, stream>>>(Ob, WoT, 4096, 1024, 1024,
                                                     (unsigned short*)nullptr, (unsigned short*)nullptr,
                                                     out, bo);
}

// Round 6
// 315.269 us; speedup vs baseline: 1.6346x; 1.0438x over previous
//
#include <hip/hip_runtime.h>
#include <hip/hip_bf16.h>

// Problem constants
// B=4, N=1024, M=4096, DQ=DC=1024, H=16, DH=64, INNER=1024, SCALE=0.125

typedef __attribute__((ext_vector_type(8))) short short8;          // 8 bf16 (MFMA A/B frag)
typedef __attribute__((ext_vector_type(8))) unsigned short u16x8;
typedef __attribute__((ext_vector_type(4))) float f32x4;

static __device__ __forceinline__ void gload_lds16(const void* g, void* l) {
  __builtin_amdgcn_global_load_lds((const __attribute__((address_space(1))) void*)g,
                                   (__attribute__((address_space(3))) void*)l, 16, 0, 0);
}

static __device__ __forceinline__ unsigned short f2bf(float f) {
  __hip_bfloat16 h = __float2bfloat16(f);
  unsigned short u;
  __builtin_memcpy(&u, &h, 2);
  return u;
}

static __device__ __forceinline__ float bf2f(unsigned short u) {
  unsigned int x = (unsigned int)u << 16;
  float f;
  __builtin_memcpy(&f, &x, 4);
  return f;
}

// ---------------- cast fp32 -> bf16, 8 elems/thread ----------------
__global__ __launch_bounds__(256) void cast_bf16_kernel(const float* __restrict__ in,
                                                        unsigned short* __restrict__ out,
                                                        int n8) {
  int idx = blockIdx.x * 256 + threadIdx.x;
  int stride = gridDim.x * 256;
  for (int i = idx; i < n8; i += stride) {
    const float4* p = (const float4*)in + (size_t)i * 2;
    float4 a = p[0], b = p[1];
    u16x8 r;
    r[0] = f2bf(a.x); r[1] = f2bf(a.y); r[2] = f2bf(a.z); r[3] = f2bf(a.w);
    r[4] = f2bf(b.x); r[5] = f2bf(b.y); r[6] = f2bf(b.z); r[7] = f2bf(b.w);
    *((u16x8*)out + i) = r;
  }
}

// ---------------- transpose + cast: W[K][N] fp32 -> Wt[N][K] bf16 ----------------
__global__ __launch_bounds__(256) void transpose_cast_kernel(const float* __restrict__ W,
                                                             unsigned short* __restrict__ Wt,
                                                             int K, int N) {
  __shared__ float tile[32][33];
  int n0 = blockIdx.x * 32, k0 = blockIdx.y * 32;
  int tx = threadIdx.x & 31, ty = threadIdx.x >> 5;
#pragma unroll
  for (int r = 0; r < 32; r += 8)
    tile[ty + r][tx] = W[(size_t)(k0 + ty + r) * N + n0 + tx];
  __syncthreads();
#pragma unroll
  for (int r = 0; r < 32; r += 8)
    Wt[(size_t)(n0 + ty + r) * K + k0 + tx] = f2bf(tile[tx][ty + r]);
}

// ---------------- GEMM: C[M,N] = A[M,K](bf16,row) * Bt[N,K](bf16,row)^T ----------------
// EPI 0: write Q layout [bh][n][64] bf16, PRESCALED by 0.125*log2(e)
// EPI 1: cols<1024 -> K [bh][m][64]; cols>=1024 -> V^T [bh][d][m]
// EPI 2: write fp32 outF[row*1024+col] = acc + bias[col]
template <int EPI>
__global__ __launch_bounds__(256, 2) void gemm_bt_kernel(
    const unsigned short* __restrict__ A, const unsigned short* __restrict__ Bt,
    int M, int N, int K,
    unsigned short* __restrict__ out0, unsigned short* __restrict__ out1,
    float* __restrict__ outF, const float* __restrict__ bias) {
  __shared__ unsigned short As[128 * 64];
  __shared__ unsigned short Bs[128 * 64];
  const int tid = threadIdx.x;
  const int l = tid & 63;
  const int lq = l & 15, g = l >> 4;
  const int w = tid >> 6;
  const int wr = w >> 1, wc = w & 1;
  const int m0 = blockIdx.y * 128, n0 = blockIdx.x * 128;

  f32x4 acc[4][4] = {};

  for (int k0 = 0; k0 < K; k0 += 64) {
    __syncthreads();
#pragma unroll
    for (int t = 0; t < 4; ++t) {
      int c = t * 256 + tid;
      int row = c >> 3, cb = c & 7;
      int srcoff = (cb * 16) ^ ((row & 7) << 4);
      char* la = (char*)As + t * 4096 + (tid & 192) * 16;  // wave-uniform base
      gload_lds16((const char*)(A + (size_t)(m0 + row) * K + k0) + srcoff, la);
      char* lb = (char*)Bs + t * 4096 + (tid & 192) * 16;
      gload_lds16((const char*)(Bt + (size_t)(n0 + row) * K + k0) + srcoff, lb);
    }
    __syncthreads();
#pragma unroll
    for (int ks = 0; ks < 2; ++ks) {
      short8 af[4], bfr[4];
#pragma unroll
      for (int mt = 0; mt < 4; ++mt) {
        int row = wr * 64 + mt * 16 + lq;
        af[mt] = *(const short8*)&As[row * 64 + ((ks * 32 + g * 8) ^ ((row & 7) << 3))];
      }
#pragma unroll
      for (int nt = 0; nt < 4; ++nt) {
        int row = wc * 64 + nt * 16 + lq;
        bfr[nt] = *(const short8*)&Bs[row * 64 + ((ks * 32 + g * 8) ^ ((row & 7) << 3))];
      }
#pragma unroll
      for (int mt = 0; mt < 4; ++mt)
#pragma unroll
        for (int nt = 0; nt < 4; ++nt)
          acc[mt][nt] =
              __builtin_amdgcn_mfma_f32_16x16x32_bf16(af[mt], bfr[nt], acc[mt][nt], 0, 0, 0);
    }
  }

#pragma unroll
  for (int mt = 0; mt < 4; ++mt) {
#pragma unroll
    for (int nt = 0; nt < 4; ++nt) {
      if (EPI == 1 && n0 >= 1024) {
        // V^T: [bh][d][m], 4 m-consecutive values packed per lane
        int colb = n0 - 1024 + wc * 64 + nt * 16 + lq;
        int h = colb >> 6, d = colb & 63;
        int rowb = m0 + wr * 64 + mt * 16 + g * 4;
        int b = rowb >> 12, mm = rowb & 4095;
        ushort4 pk;
        pk.x = f2bf(acc[mt][nt][0]);
        pk.y = f2bf(acc[mt][nt][1]);
        pk.z = f2bf(acc[mt][nt][2]);
        pk.w = f2bf(acc[mt][nt][3]);
        *(ushort4*)&out1[(((size_t)(b * 16 + h)) * 64 + d) * 4096 + mm] = pk;
      } else {
#pragma unroll
        for (int r = 0; r < 4; ++r) {
          int row = m0 + wr * 64 + mt * 16 + g * 4 + r;
          int col = n0 + wc * 64 + nt * 16 + lq;
          float v = acc[mt][nt][r];
          if (EPI == 0) {
            int b = row >> 10, nq = row & 1023;
            int h = col >> 6, d = col & 63;
            // fold softmax scale (0.125 * log2 e) into Q
            out0[(((size_t)(b * 16 + h)) * 1024 + nq) * 64 + d] =
                f2bf(v * 0.18033688011112042f);
          } else if (EPI == 1) {
            int b = row >> 12, mm = row & 4095;
            int h = col >> 6, d = col & 63;
            out0[(((size_t)(b * 16 + h)) * 4096 + mm) * 64 + d] = f2bf(v);
          } else {
            outF[(size_t)row * 1024 + col] = v + bias[col];
          }
        }
      }
    }
  }
}

// ---------------- fused attention (j-split partials, 64-row q-blocks) ----------------
// Round-2-verified data path, re-tiled for occupancy: 4096 blocks, each wave
// owns 16 q-rows (q-block 64). 16 q-blocks share one (bh,js) K/V chunk, so at
// 4-6 blocks/CU the resident set is only 8-12 chunks/XCD (2-3 MB < 4 MB L2).
// Q prescaled by 0.125*log2e; mask folded into MFMA C-operand (0/-1e30), clip
// then yields exactly -5*log2e for masked lanes.
__global__ __launch_bounds__(256, 4) void attn_kernel(
    const unsigned short* __restrict__ Q, const unsigned short* __restrict__ Kb,
    const unsigned short* __restrict__ VbT, const int* __restrict__ mask,
    unsigned short* __restrict__ numP, float* __restrict__ denP) {
  __shared__ unsigned short Ks[64 * 64];      // [j][d], XOR-swizzled content
  __shared__ unsigned short Vt[64 * 64];      // [d][j], XOR-swizzled content
  __shared__ unsigned short Ps[4 * 16 * 64];  // per-wave [q][j], pswz-swizzled

  const int tid = threadIdx.x;
  const int l = tid & 63, w = tid >> 6;
  const int lq = l & 15, g = l >> 4;

  // XCD-affine decode: id&7 = XCD; 16 consecutive same-XCD blocks share (bh,js)
  const int id = blockIdx.x;
  const int xcd = id & 7;
  const int k = id >> 3;       // 0..511
  const int qi = k & 15;       // 16 q-blocks per chunk
  const int pr = xcd * 32 + (k >> 4);  // 0..255
  const int bh = pr & 63, js = pr >> 6;
  const int b = bh >> 4;
  const int q0 = qi * 64 + w * 16;

  const unsigned short* Qh = Q + (size_t)bh * 1024 * 64;
  const unsigned short* Kh = Kb + (size_t)bh * 4096 * 64;
  const unsigned short* Vth = VbT + (size_t)bh * 64 * 4096;
  const int* mb = mask + b * 4096;

  const float CLIP2 = 7.213475204444817f;  // 5 * log2(e)

  // Q fragments live in registers for the whole kernel (prescaled)
  short8 qf[2];
#pragma unroll
  for (int ks = 0; ks < 2; ++ks)
    qf[ks] = *(const short8*)&Qh[(size_t)(q0 + lq) * 64 + ks * 32 + g * 8];

  f32x4 acc[4] = {};
  float denom[4] = {};
  unsigned short* Pw = &Ps[w * 1024];

  for (int jt = js * 16; jt < js * 16 + 16; ++jt) {
    const int j0 = jt * 64;
    __syncthreads();  // previous tile fully consumed
    // stage K tile [64 j][64 d] via global_load_lds, source pre-swizzled
#pragma unroll
    for (int t = 0; t < 2; ++t) {
      int c = t * 256 + tid;
      int row = c >> 3, cb = c & 7;
      int srcoff = (cb * 16) ^ ((row & 7) << 4);
      char* lk = (char*)Ks + t * 4096 + (tid & 192) * 16;
      gload_lds16((const char*)(Kh + (size_t)(j0 + row) * 64) + srcoff, lk);
    }
    // stage V^T tile [64 d][64 j] via global_load_lds from precomputed V^T
#pragma unroll
    for (int t = 0; t < 2; ++t) {
      int c = t * 256 + tid;
      int row = c >> 3, cb = c & 7;  // row = d
      int srcoff = (cb * 16) ^ ((row & 7) << 4);
      char* lv = (char*)Vt + t * 4096 + (tid & 192) * 16;
      gload_lds16((const char*)(Vth + (size_t)row * 4096 + j0) + srcoff, lv);
    }
    // per-lane mask bias for its j columns (MFMA C-operand seed)
    float mbias[4];
#pragma unroll
    for (int nt = 0; nt < 4; ++nt) mbias[nt] = mb[j0 + nt * 16 + lq] ? 0.0f : -1e30f;
    __syncthreads();

    float tmp[4] = {};
#pragma unroll
    for (int nt = 0; nt < 4; ++nt) {
      int row = nt * 16 + lq;
      short8 kf0 = *(const short8*)&Ks[row * 64 + ((g * 8) ^ ((row & 7) << 3))];
      short8 kf1 = *(const short8*)&Ks[row * 64 + ((32 + g * 8) ^ ((row & 7) << 3))];
      f32x4 s = {mbias[nt], mbias[nt], mbias[nt], mbias[nt]};
      s = __builtin_amdgcn_mfma_f32_16x16x32_bf16(qf[0], kf0, s, 0, 0, 0);
      s = __builtin_amdgcn_mfma_f32_16x16x32_bf16(qf[1], kf1, s, 0, 0, 0);
#pragma unroll
      for (int r = 0; r < 4; ++r) {
        float v = fminf(fmaxf(s[r], -CLIP2), CLIP2);  // masked -> exactly -CLIP2
        float pE = exp2f(v);
        tmp[r] += pE;
        int q = g * 4 + r;
        int j = nt * 16 + lq;
        int psw = (((q >> 2) & 3) << 4) ^ ((q & 7) << 3);
        Pw[q * 64 + (j ^ psw)] = f2bf(pE);
      }
    }
    // denominator: reduce over the 16-lane j-group
#pragma unroll
    for (int r = 0; r < 4; ++r) {
      float v = tmp[r];
      v += __shfl_xor(v, 1);
      v += __shfl_xor(v, 2);
      v += __shfl_xor(v, 4);
      v += __shfl_xor(v, 8);
      denom[r] += v;
    }

    // PV
    short8 pa[2], vbf[4][2];
    {
      int row = lq;
      int psw = (((row >> 2) & 3) << 4) ^ ((row & 7) << 3);
#pragma unroll
      for (int ks = 0; ks < 2; ++ks)
        pa[ks] = *(const short8*)&Pw[row * 64 + ((ks * 32 + g * 8) ^ psw)];
    }
#pragma unroll
    for (int dt = 0; dt < 4; ++dt) {
      int row = dt * 16 + lq;
#pragma unroll
      for (int ks = 0; ks < 2; ++ks)
        vbf[dt][ks] = *(const short8*)&Vt[row * 64 + ((ks * 32 + g * 8) ^ ((row & 7) << 3))];
    }
#pragma unroll
    for (int dt = 0; dt < 4; ++dt) {
      acc[dt] = __builtin_amdgcn_mfma_f32_16x16x32_bf16(pa[0], vbf[dt][0], acc[dt], 0, 0, 0);
      acc[dt] = __builtin_amdgcn_mfma_f32_16x16x32_bf16(pa[1], vbf[dt][1], acc[dt], 0, 0, 0);
    }
  }

  // write partial numerator (bf16) and denominator (fp32)
#pragma unroll
  for (int dt = 0; dt < 4; ++dt)
#pragma unroll
    for (int r = 0; r < 4; ++r) {
      int q = q0 + g * 4 + r;
      int d = dt * 16 + lq;
      numP[((((size_t)js * 64 + bh) * 1024 + q) * 64) + d] = f2bf(acc[dt][r]);
    }
  if (lq == 0) {
#pragma unroll
    for (int r = 0; r < 4; ++r) {
      int q = q0 + g * 4 + r;
      denP[(((size_t)js * 64 + bh) * 1024) + q] = denom[r];
    }
  }
}

// ---------------- combine j-split partials, divide, write Ob ----------------
__global__ __launch_bounds__(256) void attn_reduce_kernel(
    const unsigned short* __restrict__ numP, const float* __restrict__ denP,
    unsigned short* __restrict__ Ob) {
  int id = blockIdx.x * 256 + threadIdx.x;  // 0 .. 524287
  int d8 = id & 7;
  int q = (id >> 3) & 1023;
  int bh = id >> 13;
  int b = bh >> 4, h = bh & 15;
  float den = 0.f;
  float o[8] = {0.f, 0.f, 0.f, 0.f, 0.f, 0.f, 0.f, 0.f};
#pragma unroll
  for (int s = 0; s < 4; ++s) {
    const unsigned short* np =
        numP + ((((size_t)s * 64 + bh) * 1024 + q) * 64 + d8 * 8);
    u16x8 v = *(const u16x8*)np;
    den += denP[((size_t)s * 64 + bh) * 1024 + q];
#pragma unroll
    for (int e = 0; e < 8; ++e) o[e] += bf2f(v[e]);
  }
  float r = 1.0f / den;
  u16x8 outv;
#pragma unroll
  for (int e = 0; e < 8; ++e) outv[e] = f2bf(o[e] * r);
  *(u16x8*)&Ob[(((size_t)b * 1024 + q) * 1024) + h * 64 + d8 * 8] = outv;
}

// ---------------- launcher ----------------
extern "C" void kernel_launch(void* const* d_in, const int* in_sizes, int n_in,
                              void* d_out, int out_size, void* d_ws, size_t ws_size,
                              hipStream_t stream) {
  (void)in_sizes; (void)n_in; (void)out_size; (void)ws_size;
  const float* x    = (const float*)d_in[0];
  const float* ctx  = (const float*)d_in[1];
  const int*   mask = (const int*)d_in[2];
  const float* Wq   = (const float*)d_in[3];
  const float* Wkv  = (const float*)d_in[4];
  const float* Wo   = (const float*)d_in[5];
  const float* bo   = (const float*)d_in[6];
  float* out = (float*)d_out;

  char* ws = (char*)d_ws;
  const size_t MB = 1 << 20;
  // 0..40 MiB region is time-shared: {xb, cb} before attention, {numP, denP} after
  unsigned short* numP = (unsigned short*)(ws + 0);        // 32 MiB : [4][64][1024][64] bf16
  float*          denP = (float*)(ws + 32 * MB);           // 1 MiB  : [4][64][1024] fp32
  unsigned short* xb   = (unsigned short*)(ws + 0);        // 8 MiB  : x bf16 [4096][1024]
  unsigned short* cb   = (unsigned short*)(ws + 8 * MB);   // 32 MiB : ctx bf16 [16384][1024]
  unsigned short* WqT  = (unsigned short*)(ws + 40 * MB);  // 2 MiB
  unsigned short* WkvT = (unsigned short*)(ws + 42 * MB);  // 4 MiB
  unsigned short* WoT  = (unsigned short*)(ws + 46 * MB);  // 2 MiB
  unsigned short* Qb   = (unsigned short*)(ws + 48 * MB);  // 8 MiB  : [bh][1024][64] (prescaled)
  unsigned short* Kb   = (unsigned short*)(ws + 56 * MB);  // 32 MiB : [bh][4096][64]
  unsigned short* VbT  = (unsigned short*)(ws + 88 * MB);  // 32 MiB : [bh][64][4096]
  unsigned short* Ob   = (unsigned short*)(ws + 120 * MB); // 8 MiB  : [b][n][1024]

  cast_bf16_kernel<<<2048, 256, 0, stream>>>(x, xb, (4 * 1024 * 1024) / 8);
  cast_bf16_kernel<<<2048, 256, 0, stream>>>(ctx, cb, (16 * 1024 * 1024) / 8);
  transpose_cast_kernel<<<dim3(32, 32), 256, 0, stream>>>(Wq, WqT, 1024, 1024);
  transpose_cast_kernel<<<dim3(64, 32), 256, 0, stream>>>(Wkv, WkvT, 1024, 2048);
  transpose_cast_kernel<<<dim3(32, 32), 256, 0, stream>>>(Wo, WoT, 1024, 1024);

  gemm_bt_kernel<0><<<dim3(8, 32), 256, 0, stream>>>(xb, WqT, 4096, 1024, 1024,
                                                     Qb, (unsigned short*)nullptr,
                                                     (float*)nullptr, (const float*)nullptr);
  gemm_bt_kernel<1><<<dim3(16, 128), 256, 0, stream>>>(cb, WkvT, 16384, 2048, 1024,
                                                       Kb, VbT,
                                                       (float*)nullptr, (const float*)nullptr);
  attn_kernel<<<4096, 256, 0, stream>>>(Qb, Kb, VbT, mask, numP, denP);
  attn_reduce_kernel<<<2048, 256, 0, stream>>>(numP, denP, Ob);
  gemm_bt_kernel<2><<<dim3(8, 32), 256, 0, stream>>>(Ob, WoT, 4096, 1024, 1024,
                                                     (unsigned short*)nullptr, (unsigned short*)nullptr,
                                                     out, bo);
}

// Round 7
// 300.924 us; speedup vs baseline: 1.7126x; 1.0477x over previous
//
#include <hip/hip_runtime.h>
#include <hip/hip_bf16.h>

// Problem constants
// B=4, N=1024, M=4096, DQ=DC=1024, H=16, DH=64, INNER=1024, SCALE=0.125

typedef __attribute__((ext_vector_type(8))) short short8;          // 8 bf16 (MFMA A/B frag)
typedef __attribute__((ext_vector_type(8))) unsigned short u16x8;
typedef __attribute__((ext_vector_type(4))) float f32x4;
typedef __attribute__((ext_vector_type(16))) float f32x16;

static __device__ __forceinline__ void gload_lds16(const void* g, void* l) {
  __builtin_amdgcn_global_load_lds((const __attribute__((address_space(1))) void*)g,
                                   (__attribute__((address_space(3))) void*)l, 16, 0, 0);
}

static __device__ __forceinline__ unsigned short f2bf(float f) {
  __hip_bfloat16 h = __float2bfloat16(f);
  unsigned short u;
  __builtin_memcpy(&u, &h, 2);
  return u;
}

static __device__ __forceinline__ float bf2f(unsigned short u) {
  unsigned int x = (unsigned int)u << 16;
  float f;
  __builtin_memcpy(&f, &x, 4);
  return f;
}

// pack two floats to one u32 of 2 bf16 (verified f2bf path, low = a)
static __device__ __forceinline__ unsigned int pack_bf(float a, float b) {
  return (unsigned int)f2bf(a) | ((unsigned int)f2bf(b) << 16);
}

// ---------------- cast fp32 -> bf16, 8 elems/thread ----------------
__global__ __launch_bounds__(256) void cast_bf16_kernel(const float* __restrict__ in,
                                                        unsigned short* __restrict__ out,
                                                        int n8) {
  int idx = blockIdx.x * 256 + threadIdx.x;
  int stride = gridDim.x * 256;
  for (int i = idx; i < n8; i += stride) {
    const float4* p = (const float4*)in + (size_t)i * 2;
    float4 a = p[0], b = p[1];
    u16x8 r;
    r[0] = f2bf(a.x); r[1] = f2bf(a.y); r[2] = f2bf(a.z); r[3] = f2bf(a.w);
    r[4] = f2bf(b.x); r[5] = f2bf(b.y); r[6] = f2bf(b.z); r[7] = f2bf(b.w);
    *((u16x8*)out + i) = r;
  }
}

// ---------------- transpose + cast: W[K][N] fp32 -> Wt[N][K] bf16 ----------------
__global__ __launch_bounds__(256) void transpose_cast_kernel(const float* __restrict__ W,
                                                             unsigned short* __restrict__ Wt,
                                                             int K, int N) {
  __shared__ float tile[32][33];
  int n0 = blockIdx.x * 32, k0 = blockIdx.y * 32;
  int tx = threadIdx.x & 31, ty = threadIdx.x >> 5;
#pragma unroll
  for (int r = 0; r < 32; r += 8)
    tile[ty + r][tx] = W[(size_t)(k0 + ty + r) * N + n0 + tx];
  __syncthreads();
#pragma unroll
  for (int r = 0; r < 32; r += 8)
    Wt[(size_t)(n0 + ty + r) * K + k0 + tx] = f2bf(tile[tx][ty + r]);
}

// ---------------- GEMM: C[M,N] = A[M,K](bf16,row) * Bt[N,K](bf16,row)^T ----------------
// EPI 0: write Q layout [bh][n][64] bf16, PRESCALED by 0.125*log2(e)
// EPI 1: cols<1024 -> K [bh][m][64]; cols>=1024 -> V^T [bh][d][m]
// EPI 2: write fp32 outF[row*1024+col] = acc + bias[col]
template <int EPI>
__global__ __launch_bounds__(256, 2) void gemm_bt_kernel(
    const unsigned short* __restrict__ A, const unsigned short* __restrict__ Bt,
    int M, int N, int K,
    unsigned short* __restrict__ out0, unsigned short* __restrict__ out1,
    float* __restrict__ outF, const float* __restrict__ bias) {
  __shared__ unsigned short As[128 * 64];
  __shared__ unsigned short Bs[128 * 64];
  const int tid = threadIdx.x;
  const int l = tid & 63;
  const int lq = l & 15, g = l >> 4;
  const int w = tid >> 6;
  const int wr = w >> 1, wc = w & 1;
  const int m0 = blockIdx.y * 128, n0 = blockIdx.x * 128;

  f32x4 acc[4][4] = {};

  for (int k0 = 0; k0 < K; k0 += 64) {
    __syncthreads();
#pragma unroll
    for (int t = 0; t < 4; ++t) {
      int c = t * 256 + tid;
      int row = c >> 3, cb = c & 7;
      int srcoff = (cb * 16) ^ ((row & 7) << 4);
      char* la = (char*)As + t * 4096 + (tid & 192) * 16;  // wave-uniform base
      gload_lds16((const char*)(A + (size_t)(m0 + row) * K + k0) + srcoff, la);
      char* lb = (char*)Bs + t * 4096 + (tid & 192) * 16;
      gload_lds16((const char*)(Bt + (size_t)(n0 + row) * K + k0) + srcoff, lb);
    }
    __syncthreads();
#pragma unroll
    for (int ks = 0; ks < 2; ++ks) {
      short8 af[4], bfr[4];
#pragma unroll
      for (int mt = 0; mt < 4; ++mt) {
        int row = wr * 64 + mt * 16 + lq;
        af[mt] = *(const short8*)&As[row * 64 + ((ks * 32 + g * 8) ^ ((row & 7) << 3))];
      }
#pragma unroll
      for (int nt = 0; nt < 4; ++nt) {
        int row = wc * 64 + nt * 16 + lq;
        bfr[nt] = *(const short8*)&Bs[row * 64 + ((ks * 32 + g * 8) ^ ((row & 7) << 3))];
      }
#pragma unroll
      for (int mt = 0; mt < 4; ++mt)
#pragma unroll
        for (int nt = 0; nt < 4; ++nt)
          acc[mt][nt] =
              __builtin_amdgcn_mfma_f32_16x16x32_bf16(af[mt], bfr[nt], acc[mt][nt], 0, 0, 0);
    }
  }

#pragma unroll
  for (int mt = 0; mt < 4; ++mt) {
#pragma unroll
    for (int nt = 0; nt < 4; ++nt) {
      if (EPI == 1 && n0 >= 1024) {
        // V^T: [bh][d][m], 4 m-consecutive values packed per lane
        int colb = n0 - 1024 + wc * 64 + nt * 16 + lq;
        int h = colb >> 6, d = colb & 63;
        int rowb = m0 + wr * 64 + mt * 16 + g * 4;
        int b = rowb >> 12, mm = rowb & 4095;
        ushort4 pk;
        pk.x = f2bf(acc[mt][nt][0]);
        pk.y = f2bf(acc[mt][nt][1]);
        pk.z = f2bf(acc[mt][nt][2]);
        pk.w = f2bf(acc[mt][nt][3]);
        *(ushort4*)&out1[(((size_t)(b * 16 + h)) * 64 + d) * 4096 + mm] = pk;
      } else {
#pragma unroll
        for (int r = 0; r < 4; ++r) {
          int row = m0 + wr * 64 + mt * 16 + g * 4 + r;
          int col = n0 + wc * 64 + nt * 16 + lq;
          float v = acc[mt][nt][r];
          if (EPI == 0) {
            int b = row >> 10, nq = row & 1023;
            int h = col >> 6, d = col & 63;
            // fold softmax scale (0.125 * log2 e) into Q
            out0[(((size_t)(b * 16 + h)) * 1024 + nq) * 64 + d] =
                f2bf(v * 0.18033688011112042f);
          } else if (EPI == 1) {
            int b = row >> 12, mm = row & 4095;
            int h = col >> 6, d = col & 63;
            out0[(((size_t)(b * 16 + h)) * 4096 + mm) * 64 + d] = f2bf(v);
          } else {
            outF[(size_t)row * 1024 + col] = v + bias[col];
          }
        }
      }
    }
  }
}

// ---------------- fused attention (j-split, in-register P, 32x32 MFMA) ----------------
// DS-pipe relief: P never touches LDS. Swapped QK^T (A=K, B=Q) via 32x32x16
// MFMA gives lane l = q-column: sacc reg r = S^T[j=(r&3)+8*(r>>2)+4*hi][q=l&31].
// Softmax lane-local (Q prescaled by 0.125*log2e; mask seeded into the MFMA
// C-operand as 0/-1e30 via per-lane int4 loads; clip yields exactly -5*log2e).
// P -> bf16 via verified f2bf packing (round-3's cvt_pk asm was the suspect),
// PV A-frags assembled with 16 shfl_xor(32)/tile. Denominator: per-lane fp32
// accumulator, ONE shfl at kernel end. DS ops/tile/wave: ~50 -> ~32 for 2x
// the q-rows. 3 blocks/CU keeps 12 chunks x 256 KB = 3 MB < 4 MB L2.
__global__ __launch_bounds__(256, 3) void attn_kernel(
    const unsigned short* __restrict__ Q, const unsigned short* __restrict__ Kb,
    const unsigned short* __restrict__ VbT, const int* __restrict__ mask,
    unsigned short* __restrict__ numP, float* __restrict__ denP) {
  __shared__ unsigned short Ks[64 * 64];  // [j][d], XOR-swizzled content
  __shared__ unsigned short Vt[64 * 64];  // [d][j], XOR-swizzled content

  const int tid = threadIdx.x;
  const int l = tid & 63, w = tid >> 6;
  const int lq = l & 31;  // q within the wave's 32-row block / row index
  const int hi = l >> 5;  // lane half

  // XCD-affine decode: id&7 = XCD; 8 consecutive same-XCD blocks share (bh,js)
  const int id = blockIdx.x;
  const int xcd = id & 7;
  const int kk = id >> 3;
  const int qi = kk & 7;
  const int pr = xcd * 32 + (kk >> 3);
  const int bh = pr & 63, js = pr >> 6;
  const int b = bh >> 4;
  const int q0 = qi * 128 + w * 32;

  const unsigned short* Qh = Q + (size_t)bh * 1024 * 64;
  const unsigned short* Kh = Kb + (size_t)bh * 4096 * 64;
  const unsigned short* Vth = VbT + (size_t)bh * 64 * 4096;
  const int* mb = mask + b * 4096;

  const float CLIP2 = 7.213475204444817f;  // 5 * log2(e)

  // Q fragments (B-operand): lane holds Q[q0+lq][kc*16 + hi*8 + e], prescaled
  short8 qf[4];
#pragma unroll
  for (int kc = 0; kc < 4; ++kc)
    qf[kc] = *(const short8*)&Qh[(size_t)(q0 + lq) * 64 + kc * 16 + hi * 8];

  f32x16 oacc[2] = {};
  float den = 0.f;

  for (int jt = js * 16; jt < js * 16 + 16; ++jt) {
    const int j0 = jt * 64;
    __syncthreads();  // previous tile fully consumed
    // stage K tile [64 j][64 d] via global_load_lds, source pre-swizzled
#pragma unroll
    for (int t = 0; t < 2; ++t) {
      int c = t * 256 + tid;
      int row = c >> 3, cb = c & 7;
      int srcoff = (cb * 16) ^ ((row & 7) << 4);
      char* lk = (char*)Ks + t * 4096 + (tid & 192) * 16;
      gload_lds16((const char*)(Kh + (size_t)(j0 + row) * 64) + srcoff, lk);
    }
    // stage V^T tile [64 d][64 j] via global_load_lds from precomputed V^T
#pragma unroll
    for (int t = 0; t < 2; ++t) {
      int c = t * 256 + tid;
      int row = c >> 3, cb = c & 7;  // row = d
      int srcoff = (cb * 16) ^ ((row & 7) << 4);
      char* lv = (char*)Vt + t * 4096 + (tid & 192) * 16;
      gload_lds16((const char*)(Vth + (size_t)row * 4096 + j0) + srcoff, lv);
    }
    __syncthreads();

#pragma unroll
    for (int half = 0; half < 2; ++half) {
      // seed S accumulator with mask bias: reg r covers j-row (r&3)+8*(r>>2)+4*hi
      f32x16 sacc;
#pragma unroll
      for (int bq = 0; bq < 4; ++bq) {
        int4 m4 = *(const int4*)&mb[j0 + half * 32 + bq * 8 + hi * 4];
        sacc[bq * 4 + 0] = m4.x ? 0.0f : -1e30f;
        sacc[bq * 4 + 1] = m4.y ? 0.0f : -1e30f;
        sacc[bq * 4 + 2] = m4.z ? 0.0f : -1e30f;
        sacc[bq * 4 + 3] = m4.w ? 0.0f : -1e30f;
      }
      // S^T = K * Q^T  (A = K rows j = half*32+lq, B = Q cols q)
#pragma unroll
      for (int kc = 0; kc < 4; ++kc) {
        int row = half * 32 + lq;
        short8 kf = *(const short8*)&Ks[row * 64 + ((kc * 16 + hi * 8) ^ ((row & 7) << 3))];
        sacc = __builtin_amdgcn_mfma_f32_32x32x16_bf16(kf, qf[kc], sacc, 0, 0, 0);
      }
      // softmax: clip then exp2; masked rows hit -CLIP2 exactly
#pragma unroll
      for (int r = 0; r < 16; ++r) {
        float v = fminf(fmaxf(sacc[r], -CLIP2), CLIP2);
        float p = exp2f(v);
        sacc[r] = p;
        den += p;
      }
      // pack to bf16 words: wds[i] = (P[j=4hi+8*(i>>1)+2*(i&1)], P[j+1]), j rel. half*32
      unsigned int wds[8], xw[8];
#pragma unroll
      for (int i = 0; i < 8; ++i) wds[i] = pack_bf(sacc[i * 2], sacc[i * 2 + 1]);
#pragma unroll
      for (int i = 0; i < 8; ++i) xw[i] = __shfl_xor((int)wds[i], 32);
      // PV: assemble A-frag (lane needs P[q=lq][j=kt*16+hi*8+e]) and multiply
#pragma unroll
      for (int kt = 0; kt < 2; ++kt) {
        unsigned int f0 = hi ? xw[(2 * kt + 1) * 2 + 0] : wds[(2 * kt) * 2 + 0];
        unsigned int f1 = hi ? xw[(2 * kt + 1) * 2 + 1] : wds[(2 * kt) * 2 + 1];
        unsigned int f2 = hi ? wds[(2 * kt + 1) * 2 + 0] : xw[(2 * kt) * 2 + 0];
        unsigned int f3 = hi ? wds[(2 * kt + 1) * 2 + 1] : xw[(2 * kt) * 2 + 1];
        union { unsigned int u[4]; short8 s; } pa;
        pa.u[0] = f0; pa.u[1] = f1; pa.u[2] = f2; pa.u[3] = f3;
#pragma unroll
        for (int dt = 0; dt < 2; ++dt) {
          int row = dt * 32 + lq;
          short8 vf = *(const short8*)&Vt[row * 64 +
              ((half * 32 + kt * 16 + hi * 8) ^ ((row & 7) << 3))];
          oacc[dt] = __builtin_amdgcn_mfma_f32_32x32x16_bf16(pa.s, vf, oacc[dt], 0, 0, 0);
        }
      }
    }
  }

  // denominator: lanes l and l^32 hold disjoint j-sums for the same q
  den += __shfl_xor(den, 32);
  if (l < 32) denP[(((size_t)js * 64 + bh) * 1024) + q0 + l] = den;

  // numerator partials: q from reg index, d from lane
#pragma unroll
  for (int dt = 0; dt < 2; ++dt)
#pragma unroll
    for (int r = 0; r < 16; ++r) {
      int q = q0 + (r & 3) + 8 * (r >> 2) + 4 * hi;
      int d = dt * 32 + lq;
      numP[((((size_t)js * 64 + bh) * 1024 + q) * 64) + d] = f2bf(oacc[dt][r]);
    }
}

// ---------------- combine j-split partials, divide, write Ob ----------------
__global__ __launch_bounds__(256) void attn_reduce_kernel(
    const unsigned short* __restrict__ numP, const float* __restrict__ denP,
    unsigned short* __restrict__ Ob) {
  int id = blockIdx.x * 256 + threadIdx.x;  // 0 .. 524287
  int d8 = id & 7;
  int q = (id >> 3) & 1023;
  int bh = id >> 13;
  int b = bh >> 4, h = bh & 15;
  float den = 0.f;
  float o[8] = {0.f, 0.f, 0.f, 0.f, 0.f, 0.f, 0.f, 0.f};
#pragma unroll
  for (int s = 0; s < 4; ++s) {
    const unsigned short* np =
        numP + ((((size_t)s * 64 + bh) * 1024 + q) * 64 + d8 * 8);
    u16x8 v = *(const u16x8*)np;
    den += denP[((size_t)s * 64 + bh) * 1024 + q];
#pragma unroll
    for (int e = 0; e < 8; ++e) o[e] += bf2f(v[e]);
  }
  float r = 1.0f / den;
  u16x8 outv;
#pragma unroll
  for (int e = 0; e < 8; ++e) outv[e] = f2bf(o[e] * r);
  *(u16x8*)&Ob[(((size_t)b * 1024 + q) * 1024) + h * 64 + d8 * 8] = outv;
}

// ---------------- launcher ----------------
extern "C" void kernel_launch(void* const* d_in, const int* in_sizes, int n_in,
                              void* d_out, int out_size, void* d_ws, size_t ws_size,
                              hipStream_t stream) {
  (void)in_sizes; (void)n_in; (void)out_size; (void)ws_size;
  const float* x    = (const float*)d_in[0];
  const float* ctx  = (const float*)d_in[1];
  const int*   mask = (const int*)d_in[2];
  const float* Wq   = (const float*)d_in[3];
  const float* Wkv  = (const float*)d_in[4];
  const float* Wo   = (const float*)d_in[5];
  const float* bo   = (const float*)d_in[6];
  float* out = (float*)d_out;

  char* ws = (char*)d_ws;
  const size_t MB = 1 << 20;
  // 0..40 MiB region is time-shared: {xb, cb} before attention, {numP, denP} after
  unsigned short* numP = (unsigned short*)(ws + 0);        // 32 MiB : [4][64][1024][64] bf16
  float*          denP = (float*)(ws + 32 * MB);           // 1 MiB  : [4][64][1024] fp32
  unsigned short* xb   = (unsigned short*)(ws + 0);        // 8 MiB  : x bf16 [4096][1024]
  unsigned short* cb   = (unsigned short*)(ws + 8 * MB);   // 32 MiB : ctx bf16 [16384][1024]
  unsigned short* WqT  = (unsigned short*)(ws + 40 * MB);  // 2 MiB
  unsigned short* WkvT = (unsigned short*)(ws + 42 * MB);  // 4 MiB
  unsigned short* WoT  = (unsigned short*)(ws + 46 * MB);  // 2 MiB
  unsigned short* Qb   = (unsigned short*)(ws + 48 * MB);  // 8 MiB  : [bh][1024][64] (prescaled)
  unsigned short* Kb   = (unsigned short*)(ws + 56 * MB);  // 32 MiB : [bh][4096][64]
  unsigned short* VbT  = (unsigned short*)(ws + 88 * MB);  // 32 MiB : [bh][64][4096]
  unsigned short* Ob   = (unsigned short*)(ws + 120 * MB); // 8 MiB  : [b][n][1024]

  cast_bf16_kernel<<<2048, 256, 0, stream>>>(x, xb, (4 * 1024 * 1024) / 8);
  cast_bf16_kernel<<<2048, 256, 0, stream>>>(ctx, cb, (16 * 1024 * 1024) / 8);
  transpose_cast_kernel<<<dim3(32, 32), 256, 0, stream>>>(Wq, WqT, 1024, 1024);
  transpose_cast_kernel<<<dim3(64, 32), 256, 0, stream>>>(Wkv, WkvT, 1024, 2048);
  transpose_cast_kernel<<<dim3(32, 32), 256, 0, stream>>>(Wo, WoT, 1024, 1024);

  gemm_bt_kernel<0><<<dim3(8, 32), 256, 0, stream>>>(xb, WqT, 4096, 1024, 1024,
                                                     Qb, (unsigned short*)nullptr,
                                                     (float*)nullptr, (const float*)nullptr);
  gemm_bt_kernel<1><<<dim3(16, 128), 256, 0, stream>>>(cb, WkvT, 16384, 2048, 1024,
                                                       Kb, VbT,
                                                       (float*)nullptr, (const float*)nullptr);
  attn_kernel<<<2048, 256, 0, stream>>>(Qb, Kb, VbT, mask, numP, denP);
  attn_reduce_kernel<<<2048, 256, 0, stream>>>(numP, denP, Ob);
  gemm_bt_kernel<2><<<dim3(8, 32), 256, 0, stream>>>(Ob, WoT, 4096, 1024, 1024,
                                                     (unsigned short*)nullptr, (unsigned short*)nullptr,
                                                     out, bo);
}

// Round 8
// 271.453 us; speedup vs baseline: 1.8985x; 1.1086x over previous
//
#include <hip/hip_runtime.h>
#include <hip/hip_bf16.h>

// Problem constants
// B=4, N=1024, M=4096, DQ=DC=1024, H=16, DH=64, INNER=1024, SCALE=0.125

typedef __attribute__((ext_vector_type(8))) short short8;          // 8 bf16 (MFMA A/B frag)
typedef __attribute__((ext_vector_type(8))) unsigned short u16x8;
typedef __attribute__((ext_vector_type(4))) float f32x4;
typedef __attribute__((ext_vector_type(16))) float f32x16;

static __device__ __forceinline__ void gload_lds16(const void* g, void* l) {
  __builtin_amdgcn_global_load_lds((const __attribute__((address_space(1))) void*)g,
                                   (__attribute__((address_space(3))) void*)l, 16, 0, 0);
}

static __device__ __forceinline__ unsigned short f2bf(float f) {
  __hip_bfloat16 h = __float2bfloat16(f);
  unsigned short u;
  __builtin_memcpy(&u, &h, 2);
  return u;
}

static __device__ __forceinline__ float bf2f(unsigned short u) {
  unsigned int x = (unsigned int)u << 16;
  float f;
  __builtin_memcpy(&f, &x, 4);
  return f;
}

// pack two positive floats to one u32 of 2 bf16 (round-half-up): 3 VALU ops.
// perm sel [6,7,2,3]: dst = {lo16 = a.hi16, hi16 = b.hi16}
static __device__ __forceinline__ unsigned int pack_rnd(float a, float b) {
  unsigned int ua, ub;
  __builtin_memcpy(&ua, &a, 4);
  __builtin_memcpy(&ub, &b, 4);
  return __builtin_amdgcn_perm(ua + 0x8000u, ub + 0x8000u, 0x03020706u);
}

// ---------------- cast fp32 -> bf16, 8 elems/thread ----------------
__global__ __launch_bounds__(256) void cast_bf16_kernel(const float* __restrict__ in,
                                                        unsigned short* __restrict__ out,
                                                        int n8) {
  int idx = blockIdx.x * 256 + threadIdx.x;
  int stride = gridDim.x * 256;
  for (int i = idx; i < n8; i += stride) {
    const float4* p = (const float4*)in + (size_t)i * 2;
    float4 a = p[0], b = p[1];
    u16x8 r;
    r[0] = f2bf(a.x); r[1] = f2bf(a.y); r[2] = f2bf(a.z); r[3] = f2bf(a.w);
    r[4] = f2bf(b.x); r[5] = f2bf(b.y); r[6] = f2bf(b.z); r[7] = f2bf(b.w);
    *((u16x8*)out + i) = r;
  }
}

// ---------------- mask -> fp32 additive bias (0 / -1e30) ----------------
__global__ __launch_bounds__(256) void mask_bias_kernel(const int* __restrict__ mask,
                                                        float* __restrict__ bias, int n) {
  int i = blockIdx.x * 256 + threadIdx.x;
  if (i < n) bias[i] = mask[i] ? 0.0f : -1e30f;
}

// ---------------- transpose + cast: W[K][N] fp32 -> Wt[N][K] bf16 ----------------
__global__ __launch_bounds__(256) void transpose_cast_kernel(const float* __restrict__ W,
                                                             unsigned short* __restrict__ Wt,
                                                             int K, int N) {
  __shared__ float tile[32][33];
  int n0 = blockIdx.x * 32, k0 = blockIdx.y * 32;
  int tx = threadIdx.x & 31, ty = threadIdx.x >> 5;
#pragma unroll
  for (int r = 0; r < 32; r += 8)
    tile[ty + r][tx] = W[(size_t)(k0 + ty + r) * N + n0 + tx];
  __syncthreads();
#pragma unroll
  for (int r = 0; r < 32; r += 8)
    Wt[(size_t)(n0 + ty + r) * K + k0 + tx] = f2bf(tile[tx][ty + r]);
}

// ---------------- GEMM: C[M,N] = A[M,K](bf16,row) * Bt[N,K](bf16,row)^T ----------------
// EPI 0: write Q layout [bh][n][64] bf16, PRESCALED by 0.125*log2(e)
// EPI 1: cols<1024 -> K [bh][m][64]; cols>=1024 -> V^T [bh][d][m]
// EPI 2: write fp32 outF[row*1024+col] = acc + bias[col]
template <int EPI>
__global__ __launch_bounds__(256, 2) void gemm_bt_kernel(
    const unsigned short* __restrict__ A, const unsigned short* __restrict__ Bt,
    int M, int N, int K,
    unsigned short* __restrict__ out0, unsigned short* __restrict__ out1,
    float* __restrict__ outF, const float* __restrict__ bias) {
  __shared__ unsigned short As[128 * 64];
  __shared__ unsigned short Bs[128 * 64];
  const int tid = threadIdx.x;
  const int l = tid & 63;
  const int lq = l & 15, g = l >> 4;
  const int w = tid >> 6;
  const int wr = w >> 1, wc = w & 1;
  const int m0 = blockIdx.y * 128, n0 = blockIdx.x * 128;

  f32x4 acc[4][4] = {};

  for (int k0 = 0; k0 < K; k0 += 64) {
    __syncthreads();
#pragma unroll
    for (int t = 0; t < 4; ++t) {
      int c = t * 256 + tid;
      int row = c >> 3, cb = c & 7;
      int srcoff = (cb * 16) ^ ((row & 7) << 4);
      char* la = (char*)As + t * 4096 + (tid & 192) * 16;  // wave-uniform base
      gload_lds16((const char*)(A + (size_t)(m0 + row) * K + k0) + srcoff, la);
      char* lb = (char*)Bs + t * 4096 + (tid & 192) * 16;
      gload_lds16((const char*)(Bt + (size_t)(n0 + row) * K + k0) + srcoff, lb);
    }
    __syncthreads();
#pragma unroll
    for (int ks = 0; ks < 2; ++ks) {
      short8 af[4], bfr[4];
#pragma unroll
      for (int mt = 0; mt < 4; ++mt) {
        int row = wr * 64 + mt * 16 + lq;
        af[mt] = *(const short8*)&As[row * 64 + ((ks * 32 + g * 8) ^ ((row & 7) << 3))];
      }
#pragma unroll
      for (int nt = 0; nt < 4; ++nt) {
        int row = wc * 64 + nt * 16 + lq;
        bfr[nt] = *(const short8*)&Bs[row * 64 + ((ks * 32 + g * 8) ^ ((row & 7) << 3))];
      }
#pragma unroll
      for (int mt = 0; mt < 4; ++mt)
#pragma unroll
        for (int nt = 0; nt < 4; ++nt)
          acc[mt][nt] =
              __builtin_amdgcn_mfma_f32_16x16x32_bf16(af[mt], bfr[nt], acc[mt][nt], 0, 0, 0);
    }
  }

#pragma unroll
  for (int mt = 0; mt < 4; ++mt) {
#pragma unroll
    for (int nt = 0; nt < 4; ++nt) {
      if (EPI == 1 && n0 >= 1024) {
        // V^T: [bh][d][m], 4 m-consecutive values packed per lane
        int colb = n0 - 1024 + wc * 64 + nt * 16 + lq;
        int h = colb >> 6, d = colb & 63;
        int rowb = m0 + wr * 64 + mt * 16 + g * 4;
        int b = rowb >> 12, mm = rowb & 4095;
        ushort4 pk;
        pk.x = f2bf(acc[mt][nt][0]);
        pk.y = f2bf(acc[mt][nt][1]);
        pk.z = f2bf(acc[mt][nt][2]);
        pk.w = f2bf(acc[mt][nt][3]);
        *(ushort4*)&out1[(((size_t)(b * 16 + h)) * 64 + d) * 4096 + mm] = pk;
      } else {
#pragma unroll
        for (int r = 0; r < 4; ++r) {
          int row = m0 + wr * 64 + mt * 16 + g * 4 + r;
          int col = n0 + wc * 64 + nt * 16 + lq;
          float v = acc[mt][nt][r];
          if (EPI == 0) {
            int b = row >> 10, nq = row & 1023;
            int h = col >> 6, d = col & 63;
            // fold softmax scale (0.125 * log2 e) into Q
            out0[(((size_t)(b * 16 + h)) * 1024 + nq) * 64 + d] =
                f2bf(v * 0.18033688011112042f);
          } else if (EPI == 1) {
            int b = row >> 12, mm = row & 4095;
            int h = col >> 6, d = col & 63;
            out0[(((size_t)(b * 16 + h)) * 4096 + mm) * 64 + d] = f2bf(v);
          } else {
            outF[(size_t)row * 1024 + col] = v + bias[col];
          }
        }
      }
    }
  }
}

// ---------------- fused attention (j-split, in-register P, zero-shuffle) ----------------
// Swapped QK^T (A=K, B=Q) via 32x32x16 MFMA. K stored SIGMA-PERMUTED in LDS:
// LDS row rr holds K[sigma(rr)] where sigma swaps addr bits 2<->3 (involution).
// Then the QK^T C-layout (rr=(r&3)+8*(r>>2)+4*hi) delivers each lane's regs as
// j = (r&7) + 8*hi + 16*(r>>3): PV A-frag for kt = regs 8kt..8kt+7, in order.
// NO cross-lane exchange, no hi-selects. P packed by v_perm (round-half-up).
// Mask folded as precomputed fp32 bias seeded into the MFMA C-operand (clip
// then yields exactly -5*log2e for masked). Q prescaled by 0.125*log2e.
// Denominator: per-lane fp32 accumulator, one shfl_xor(32) at kernel end.
__global__ __launch_bounds__(256, 3) void attn_kernel(
    const unsigned short* __restrict__ Q, const unsigned short* __restrict__ Kb,
    const unsigned short* __restrict__ VbT, const float* __restrict__ maskb,
    unsigned short* __restrict__ numP, float* __restrict__ denP) {
  __shared__ unsigned short Ks[64 * 64];  // [sigma'd j][d], XOR-swizzled content
  __shared__ unsigned short Vt[64 * 64];  // [d][j], XOR-swizzled content

  const int tid = threadIdx.x;
  const int l = tid & 63, w = tid >> 6;
  const int lq = l & 31;  // q within the wave's 32-row block / row index
  const int hi = l >> 5;  // lane half

  // XCD-affine decode: id&7 = XCD; 8 consecutive same-XCD blocks share (bh,js)
  const int id = blockIdx.x;
  const int xcd = id & 7;
  const int kk = id >> 3;
  const int qi = kk & 7;
  const int pr = xcd * 32 + (kk >> 3);
  const int bh = pr & 63, js = pr >> 6;
  const int b = bh >> 4;
  const int q0 = qi * 128 + w * 32;

  const unsigned short* Qh = Q + (size_t)bh * 1024 * 64;
  const unsigned short* Kh = Kb + (size_t)bh * 4096 * 64;
  const unsigned short* Vth = VbT + (size_t)bh * 64 * 4096;
  const float* bb = maskb + b * 4096;

  const float CLIP2 = 7.213475204444817f;  // 5 * log2(e)

  // Q fragments (B-operand): lane holds Q[q0+lq][kc*16 + hi*8 + e], prescaled
  short8 qf[4];
#pragma unroll
  for (int kc = 0; kc < 4; ++kc)
    qf[kc] = *(const short8*)&Qh[(size_t)(q0 + lq) * 64 + kc * 16 + hi * 8];

  f32x16 oacc[2] = {};
  float den = 0.f;

  for (int jt = js * 16; jt < js * 16 + 16; ++jt) {
    const int j0 = jt * 64;
    __syncthreads();  // previous tile fully consumed
    // stage K tile via global_load_lds: dest row = rr, source row = sigma(rr)
    // (swap bits 2<->3 of the low 5 bits), source column pre-XOR-swizzled
#pragma unroll
    for (int t = 0; t < 2; ++t) {
      int c = t * 256 + tid;
      int row = c >> 3, cb = c & 7;
      int jrow = (row & 0x33) | ((row & 4) << 1) | ((row & 8) >> 1);
      int srcoff = (cb * 16) ^ ((row & 7) << 4);
      char* lk = (char*)Ks + t * 4096 + (tid & 192) * 16;
      gload_lds16((const char*)(Kh + (size_t)(j0 + jrow) * 64) + srcoff, lk);
    }
    // stage V^T tile [64 d][64 j] (natural j order) from precomputed V^T
#pragma unroll
    for (int t = 0; t < 2; ++t) {
      int c = t * 256 + tid;
      int row = c >> 3, cb = c & 7;  // row = d
      int srcoff = (cb * 16) ^ ((row & 7) << 4);
      char* lv = (char*)Vt + t * 4096 + (tid & 192) * 16;
      gload_lds16((const char*)(Vth + (size_t)row * 4096 + j0) + srcoff, lv);
    }
    __syncthreads();

#pragma unroll
    for (int half = 0; half < 2; ++half) {
      // seed S accumulator with mask bias at j = sigma-mapped reg position:
      // reg r (bq=r>>2), lane hi -> j = (r&3) + ((bq&1)<<2) + (hi<<3) + ((bq>>1)<<4)
      f32x16 sacc;
#pragma unroll
      for (int bq = 0; bq < 4; ++bq) {
        f32x4 m4 = *(const f32x4*)&bb[j0 + half * 32 + ((bq & 1) << 2) + (hi << 3) +
                                      ((bq >> 1) << 4)];
        sacc[bq * 4 + 0] = m4[0];
        sacc[bq * 4 + 1] = m4[1];
        sacc[bq * 4 + 2] = m4[2];
        sacc[bq * 4 + 3] = m4[3];
      }
      // S^T = K * Q^T  (A = permuted-K LDS rows, B = Q cols q)
#pragma unroll
      for (int kc = 0; kc < 4; ++kc) {
        int row = half * 32 + lq;
        short8 kf = *(const short8*)&Ks[row * 64 + ((kc * 16 + hi * 8) ^ ((row & 7) << 3))];
        sacc = __builtin_amdgcn_mfma_f32_32x32x16_bf16(kf, qf[kc], sacc, 0, 0, 0);
      }
      // softmax: clip then exp2; masked rows hit -CLIP2 exactly
#pragma unroll
      for (int r = 0; r < 16; ++r) {
        float v = fminf(fmaxf(sacc[r], -CLIP2), CLIP2);
        float p = exp2f(v);
        sacc[r] = p;
        den += p;
      }
      // pack pairs (reg 2i, 2i+1): wds[i] holds P for A-frag word i directly
      unsigned int wds[8];
#pragma unroll
      for (int i = 0; i < 8; ++i) wds[i] = pack_rnd(sacc[i * 2], sacc[i * 2 + 1]);
      // PV: A-frag for kt = wds[4kt..4kt+3], no exchange needed
#pragma unroll
      for (int kt = 0; kt < 2; ++kt) {
        union { unsigned int u[4]; short8 s; } pa;
        pa.u[0] = wds[kt * 4 + 0];
        pa.u[1] = wds[kt * 4 + 1];
        pa.u[2] = wds[kt * 4 + 2];
        pa.u[3] = wds[kt * 4 + 3];
#pragma unroll
        for (int dt = 0; dt < 2; ++dt) {
          int row = dt * 32 + lq;
          short8 vf = *(const short8*)&Vt[row * 64 +
              ((half * 32 + kt * 16 + hi * 8) ^ ((row & 7) << 3))];
          oacc[dt] = __builtin_amdgcn_mfma_f32_32x32x16_bf16(pa.s, vf, oacc[dt], 0, 0, 0);
        }
      }
    }
  }

  // denominator: lanes l and l^32 hold disjoint j-sums for the same q
  den += __shfl_xor(den, 32);
  if (l < 32) denP[(((size_t)js * 64 + bh) * 1024) + q0 + l] = den;

  // numerator partials: q from reg index (PV C-layout), d from lane
#pragma unroll
  for (int dt = 0; dt < 2; ++dt)
#pragma unroll
    for (int r = 0; r < 16; ++r) {
      int q = q0 + (r & 3) + 8 * (r >> 2) + 4 * hi;
      int d = dt * 32 + lq;
      numP[((((size_t)js * 64 + bh) * 1024 + q) * 64) + d] = f2bf(oacc[dt][r]);
    }
}

// ---------------- combine j-split partials, divide, write Ob ----------------
__global__ __launch_bounds__(256) void attn_reduce_kernel(
    const unsigned short* __restrict__ numP, const float* __restrict__ denP,
    unsigned short* __restrict__ Ob) {
  int id = blockIdx.x * 256 + threadIdx.x;  // 0 .. 524287
  int d8 = id & 7;
  int q = (id >> 3) & 1023;
  int bh = id >> 13;
  int b = bh >> 4, h = bh & 15;
  float den = 0.f;
  float o[8] = {0.f, 0.f, 0.f, 0.f, 0.f, 0.f, 0.f, 0.f};
#pragma unroll
  for (int s = 0; s < 4; ++s) {
    const unsigned short* np =
        numP + ((((size_t)s * 64 + bh) * 1024 + q) * 64 + d8 * 8);
    u16x8 v = *(const u16x8*)np;
    den += denP[((size_t)s * 64 + bh) * 1024 + q];
#pragma unroll
    for (int e = 0; e < 8; ++e) o[e] += bf2f(v[e]);
  }
  float r = 1.0f / den;
  u16x8 outv;
#pragma unroll
  for (int e = 0; e < 8; ++e) outv[e] = f2bf(o[e] * r);
  *(u16x8*)&Ob[(((size_t)b * 1024 + q) * 1024) + h * 64 + d8 * 8] = outv;
}

// ---------------- launcher ----------------
extern "C" void kernel_launch(void* const* d_in, const int* in_sizes, int n_in,
                              void* d_out, int out_size, void* d_ws, size_t ws_size,
                              hipStream_t stream) {
  (void)in_sizes; (void)n_in; (void)out_size; (void)ws_size;
  const float* x    = (const float*)d_in[0];
  const float* ctx  = (const float*)d_in[1];
  const int*   mask = (const int*)d_in[2];
  const float* Wq   = (const float*)d_in[3];
  const float* Wkv  = (const float*)d_in[4];
  const float* Wo   = (const float*)d_in[5];
  const float* bo   = (const float*)d_in[6];
  float* out = (float*)d_out;

  char* ws = (char*)d_ws;
  const size_t MB = 1 << 20;
  // 0..40 MiB region is time-shared: {xb, cb} before attention; {numP, denP,
  // maskbias} after cb is consumed by the KV-GEMM (stream-ordered).
  unsigned short* numP = (unsigned short*)(ws + 0);        // 32 MiB : [4][64][1024][64] bf16
  float*          denP = (float*)(ws + 32 * MB);           // 1 MiB  : [4][64][1024] fp32
  float*          mbias= (float*)(ws + 33 * MB);           // 64 KiB : [4][4096] fp32
  unsigned short* xb   = (unsigned short*)(ws + 0);        // 8 MiB  : x bf16 [4096][1024]
  unsigned short* cb   = (unsigned short*)(ws + 8 * MB);   // 32 MiB : ctx bf16 [16384][1024]
  unsigned short* WqT  = (unsigned short*)(ws + 40 * MB);  // 2 MiB
  unsigned short* WkvT = (unsigned short*)(ws + 42 * MB);  // 4 MiB
  unsigned short* WoT  = (unsigned short*)(ws + 46 * MB);  // 2 MiB
  unsigned short* Qb   = (unsigned short*)(ws + 48 * MB);  // 8 MiB  : [bh][1024][64] (prescaled)
  unsigned short* Kb   = (unsigned short*)(ws + 56 * MB);  // 32 MiB : [bh][4096][64]
  unsigned short* VbT  = (unsigned short*)(ws + 88 * MB);  // 32 MiB : [bh][64][4096]
  unsigned short* Ob   = (unsigned short*)(ws + 120 * MB); // 8 MiB  : [b][n][1024]

  cast_bf16_kernel<<<2048, 256, 0, stream>>>(x, xb, (4 * 1024 * 1024) / 8);
  cast_bf16_kernel<<<2048, 256, 0, stream>>>(ctx, cb, (16 * 1024 * 1024) / 8);
  transpose_cast_kernel<<<dim3(32, 32), 256, 0, stream>>>(Wq, WqT, 1024, 1024);
  transpose_cast_kernel<<<dim3(64, 32), 256, 0, stream>>>(Wkv, WkvT, 1024, 2048);
  transpose_cast_kernel<<<dim3(32, 32), 256, 0, stream>>>(Wo, WoT, 1024, 1024);

  gemm_bt_kernel<0><<<dim3(8, 32), 256, 0, stream>>>(xb, WqT, 4096, 1024, 1024,
                                                     Qb, (unsigned short*)nullptr,
                                                     (float*)nullptr, (const float*)nullptr);
  gemm_bt_kernel<1><<<dim3(16, 128), 256, 0, stream>>>(cb, WkvT, 16384, 2048, 1024,
                                                       Kb, VbT,
                                                       (float*)nullptr, (const float*)nullptr);
  // mbias overlaps the (now-dead) cb region; launched after the KV-GEMM reads cb
  mask_bias_kernel<<<64, 256, 0, stream>>>(mask, mbias, 4 * 4096);
  attn_kernel<<<2048, 256, 0, stream>>>(Qb, Kb, VbT, mbias, numP, denP);
  attn_reduce_kernel<<<2048, 256, 0, stream>>>(numP, denP, Ob);
  gemm_bt_kernel<2><<<dim3(8, 32), 256, 0, stream>>>(Ob, WoT, 4096, 1024, 1024,
                                                     (unsigned short*)nullptr, (unsigned short*)nullptr,
                                                     out, bo);
}

// Round 9
// 260.848 us; speedup vs baseline: 1.9757x; 1.0407x over previous
//
#include <hip/hip_runtime.h>
#include <hip/hip_bf16.h>

// Problem constants
// B=4, N=1024, M=4096, DQ=DC=1024, H=16, DH=64, INNER=1024, SCALE=0.125

typedef __attribute__((ext_vector_type(8))) short short8;          // 8 bf16 (MFMA A/B frag)
typedef __attribute__((ext_vector_type(8))) unsigned short u16x8;
typedef __attribute__((ext_vector_type(4))) float f32x4;
typedef __attribute__((ext_vector_type(16))) float f32x16;

static __device__ __forceinline__ void gload_lds16(const void* g, void* l) {
  __builtin_amdgcn_global_load_lds((const __attribute__((address_space(1))) void*)g,
                                   (__attribute__((address_space(3))) void*)l, 16, 0, 0);
}

static __device__ __forceinline__ unsigned short f2bf(float f) {
  __hip_bfloat16 h = __float2bfloat16(f);
  unsigned short u;
  __builtin_memcpy(&u, &h, 2);
  return u;
}

static __device__ __forceinline__ float bf2f(unsigned short u) {
  unsigned int x = (unsigned int)u << 16;
  float f;
  __builtin_memcpy(&f, &x, 4);
  return f;
}

// pack two positive floats to one u32 of 2 bf16 (round-half-up): 3 VALU ops.
static __device__ __forceinline__ unsigned int pack_rnd(float a, float b) {
  unsigned int ua, ub;
  __builtin_memcpy(&ua, &a, 4);
  __builtin_memcpy(&ub, &b, 4);
  return __builtin_amdgcn_perm(ua + 0x8000u, ub + 0x8000u, 0x03020706u);
}

// ---------------- cast fp32 -> bf16, 8 elems/thread ----------------
__global__ __launch_bounds__(256) void cast_bf16_kernel(const float* __restrict__ in,
                                                        unsigned short* __restrict__ out,
                                                        int n8) {
  int idx = blockIdx.x * 256 + threadIdx.x;
  int stride = gridDim.x * 256;
  for (int i = idx; i < n8; i += stride) {
    const float4* p = (const float4*)in + (size_t)i * 2;
    float4 a = p[0], b = p[1];
    u16x8 r;
    r[0] = f2bf(a.x); r[1] = f2bf(a.y); r[2] = f2bf(a.z); r[3] = f2bf(a.w);
    r[4] = f2bf(b.x); r[5] = f2bf(b.y); r[6] = f2bf(b.z); r[7] = f2bf(b.w);
    *((u16x8*)out + i) = r;
  }
}

// ---------------- mask -> fp32 additive bias (0 / -1e30) ----------------
__global__ __launch_bounds__(256) void mask_bias_kernel(const int* __restrict__ mask,
                                                        float* __restrict__ bias, int n) {
  int i = blockIdx.x * 256 + threadIdx.x;
  if (i < n) bias[i] = mask[i] ? 0.0f : -1e30f;
}

// ---------------- transpose + cast: W[K][N] fp32 -> Wt[N][K] bf16 ----------------
__global__ __launch_bounds__(256) void transpose_cast_kernel(const float* __restrict__ W,
                                                             unsigned short* __restrict__ Wt,
                                                             int K, int N) {
  __shared__ float tile[32][33];
  int n0 = blockIdx.x * 32, k0 = blockIdx.y * 32;
  int tx = threadIdx.x & 31, ty = threadIdx.x >> 5;
#pragma unroll
  for (int r = 0; r < 32; r += 8)
    tile[ty + r][tx] = W[(size_t)(k0 + ty + r) * N + n0 + tx];
  __syncthreads();
#pragma unroll
  for (int r = 0; r < 32; r += 8)
    Wt[(size_t)(n0 + ty + r) * K + k0 + tx] = f2bf(tile[tx][ty + r]);
}

// ---------------- GEMM: C[M,N] = A[M,K](bf16,row) * Bt[N,K](bf16,row)^T ----------------
// XCD-chunked block swizzle: same-XCD blocks share an A-panel (T1).
// EPI 0: write Q layout [bh][n][64] bf16, PRESCALED by 0.125*log2(e)
// EPI 1: cols<1024 -> K2[bh][d>>3][m][d&7]; cols>=1024 -> V2[bh][m>>3][d][m&7]
// EPI 2: write fp32 outF[row*1024+col] = acc + bias[col]
template <int EPI>
__global__ __launch_bounds__(256, 2) void gemm_bt_kernel(
    const unsigned short* __restrict__ A, const unsigned short* __restrict__ Bt,
    int M, int N, int K,
    unsigned short* __restrict__ out0, unsigned short* __restrict__ out1,
    float* __restrict__ outF, const float* __restrict__ bias) {
  __shared__ unsigned short As[128 * 64];
  __shared__ unsigned short Bs[128 * 64];
  const int tid = threadIdx.x;
  const int l = tid & 63;
  const int lq = l & 15, g = l >> 4;
  const int w = tid >> 6;
  const int wr = w >> 1, wc = w & 1;
  // XCD-chunked swizzle (nwg % 8 == 0 for all our grids)
  const int nwg = gridDim.x * gridDim.y;
  const int idl = blockIdx.y * gridDim.x + blockIdx.x;
  const int lin = (idl & 7) * (nwg >> 3) + (idl >> 3);
  const int m0 = (lin / gridDim.x) * 128, n0 = (lin % gridDim.x) * 128;

  f32x4 acc[4][4] = {};

  for (int k0 = 0; k0 < K; k0 += 64) {
    __syncthreads();
#pragma unroll
    for (int t = 0; t < 4; ++t) {
      int c = t * 256 + tid;
      int row = c >> 3, cb = c & 7;
      int srcoff = (cb * 16) ^ ((row & 7) << 4);
      char* la = (char*)As + t * 4096 + (tid & 192) * 16;  // wave-uniform base
      gload_lds16((const char*)(A + (size_t)(m0 + row) * K + k0) + srcoff, la);
      char* lb = (char*)Bs + t * 4096 + (tid & 192) * 16;
      gload_lds16((const char*)(Bt + (size_t)(n0 + row) * K + k0) + srcoff, lb);
    }
    __syncthreads();
#pragma unroll
    for (int ks = 0; ks < 2; ++ks) {
      short8 af[4], bfr[4];
#pragma unroll
      for (int mt = 0; mt < 4; ++mt) {
        int row = wr * 64 + mt * 16 + lq;
        af[mt] = *(const short8*)&As[row * 64 + ((ks * 32 + g * 8) ^ ((row & 7) << 3))];
      }
#pragma unroll
      for (int nt = 0; nt < 4; ++nt) {
        int row = wc * 64 + nt * 16 + lq;
        bfr[nt] = *(const short8*)&Bs[row * 64 + ((ks * 32 + g * 8) ^ ((row & 7) << 3))];
      }
#pragma unroll
      for (int mt = 0; mt < 4; ++mt)
#pragma unroll
        for (int nt = 0; nt < 4; ++nt)
          acc[mt][nt] =
              __builtin_amdgcn_mfma_f32_16x16x32_bf16(af[mt], bfr[nt], acc[mt][nt], 0, 0, 0);
    }
  }

#pragma unroll
  for (int mt = 0; mt < 4; ++mt) {
#pragma unroll
    for (int nt = 0; nt < 4; ++nt) {
      if (EPI == 1 && n0 >= 1024) {
        // V2[bh][m>>3][d][m&7]: 4 m-consecutive values packed per lane
        int colb = n0 - 1024 + wc * 64 + nt * 16 + lq;
        int h = colb >> 6, d = colb & 63;
        int rowb = m0 + wr * 64 + mt * 16 + g * 4;
        int b = rowb >> 12, mm = rowb & 4095;
        ushort4 pk;
        pk.x = f2bf(acc[mt][nt][0]);
        pk.y = f2bf(acc[mt][nt][1]);
        pk.z = f2bf(acc[mt][nt][2]);
        pk.w = f2bf(acc[mt][nt][3]);
        size_t off = (((size_t)(b * 16 + h) * 512 + (mm >> 3)) * 64 + d) * 8 + (mm & 7);
        *(ushort4*)&out1[off] = pk;
      } else {
#pragma unroll
        for (int r = 0; r < 4; ++r) {
          int row = m0 + wr * 64 + mt * 16 + g * 4 + r;
          int col = n0 + wc * 64 + nt * 16 + lq;
          float v = acc[mt][nt][r];
          if (EPI == 0) {
            int b = row >> 10, nq = row & 1023;
            int h = col >> 6, d = col & 63;
            // fold softmax scale (0.125 * log2 e) into Q
            out0[(((size_t)(b * 16 + h)) * 1024 + nq) * 64 + d] =
                f2bf(v * 0.18033688011112042f);
          } else if (EPI == 1) {
            // K2[bh][d>>3][m][d&7]
            int b = row >> 12, mm = row & 4095;
            int h = col >> 6, d = col & 63;
            size_t off = (((size_t)(b * 16 + h) * 8 + (d >> 3)) * 4096 + mm) * 8 + (d & 7);
            out0[off] = f2bf(v);
          } else {
            outF[(size_t)row * 1024 + col] = v + bias[col];
          }
        }
      }
    }
  }
}

// ---------------- fused attention (j-split, in-register P, conflict-free LDS) ----------------
// Swapped QK^T (A=K, B=Q) via 32x32x16 MFMA, sigma-permuted K rows (round-8
// verified). NEW: d-block-major LDS geometry — K_lds[db=d/8][j][8d],
// Vt_lds[jb=j/8][d][8j] — so every frag read is 32 lanes x consecutive 16B:
// ZERO bank conflicts, loop-invariant addresses (no per-read XOR math).
// Global K2/V2 layouts (from KV-GEMM epilogue) make staging coalesced.
// Mask bias seeded into MFMA C-operand; clamp via fmed3; P packed by v_perm.
__global__ __launch_bounds__(256, 3) void attn_kernel(
    const unsigned short* __restrict__ K2, const unsigned short* __restrict__ V2,
    const unsigned short* __restrict__ Q, const float* __restrict__ maskb,
    unsigned short* __restrict__ numP, float* __restrict__ denP) {
  __shared__ unsigned short Ks[8 * 64 * 8];  // [db][j (sigma'd)][8 d-elems]
  __shared__ unsigned short Vt[8 * 64 * 8];  // [jb][d][8 j-elems]

  const int tid = threadIdx.x;
  const int l = tid & 63, w = tid >> 6;
  const int lq = l & 31;  // q within the wave's 32-row block / row index
  const int hi = l >> 5;  // lane half

  // XCD-affine decode: id&7 = XCD; 8 consecutive same-XCD blocks share (bh,js)
  const int id = blockIdx.x;
  const int xcd = id & 7;
  const int kk = id >> 3;
  const int qi = kk & 7;
  const int pr = xcd * 32 + (kk >> 3);
  const int bh = pr & 63, js = pr >> 6;
  const int b = bh >> 4;
  const int q0 = qi * 128 + w * 32;

  const unsigned short* Qh = Q + (size_t)bh * 1024 * 64;
  const unsigned short* Kh = K2 + (size_t)bh * 8 * 4096 * 8;   // [db][m][8]
  const unsigned short* Vh = V2 + (size_t)bh * 512 * 64 * 8;   // [jb][d][8]
  const float* bb = maskb + b * 4096;

  const float CLIP2 = 7.213475204444817f;  // 5 * log2(e)

  // Q fragments (B-operand): lane holds Q[q0+lq][kc*16 + hi*8 + e], prescaled
  short8 qf[4];
#pragma unroll
  for (int kc = 0; kc < 4; ++kc)
    qf[kc] = *(const short8*)&Qh[(size_t)(q0 + lq) * 64 + kc * 16 + hi * 8];

  f32x16 oacc[2] = {};
  float den = 0.f;

  for (int jt = js * 16; jt < js * 16 + 16; ++jt) {
    const int j0 = jt * 64;
    __syncthreads();  // previous tile fully consumed
    // stage K: LDS slot (db, jj) <- K2[bh][db][j0 + sigma(jj)][0..8)
    // sigma swaps bits 2<->3 (involution); source is 16B chunks of a
    // contiguous 1KB region per db (coalesced, permuted within-wave).
#pragma unroll
    for (int t = 0; t < 2; ++t) {
      int c = t * 256 + tid;
      int db = c >> 6, jj = c & 63;
      int sig = (jj & 0x33) | ((jj & 4) << 1) | ((jj & 8) >> 1);
      char* lk = (char*)Ks + t * 4096 + (tid & 192) * 16;
      gload_lds16((const char*)(Kh + ((size_t)db * 4096 + j0 + sig) * 8), lk);
    }
    // stage V: LDS slot (jb, d) <- V2[bh][j0/8 + jb][d][0..8) (fully coalesced)
#pragma unroll
    for (int t = 0; t < 2; ++t) {
      int c = t * 256 + tid;
      int jb = c >> 6, d = c & 63;
      char* lv = (char*)Vt + t * 4096 + (tid & 192) * 16;
      gload_lds16((const char*)(Vh + ((size_t)((j0 >> 3) + jb) * 64 + d) * 8), lv);
    }
    __syncthreads();

#pragma unroll
    for (int half = 0; half < 2; ++half) {
      // seed S accumulator with mask bias at sigma-mapped reg position:
      // reg r (bq=r>>2) -> j = (r&3) + 4*(bq&1) + 8*hi + 16*(bq>>1)
      f32x16 sacc;
#pragma unroll
      for (int bq = 0; bq < 4; ++bq) {
        f32x4 m4 = *(const f32x4*)&bb[j0 + half * 32 + ((bq & 1) << 2) + (hi << 3) +
                                      ((bq >> 1) << 4)];
        sacc[bq * 4 + 0] = m4[0];
        sacc[bq * 4 + 1] = m4[1];
        sacc[bq * 4 + 2] = m4[2];
        sacc[bq * 4 + 3] = m4[3];
      }
      // S^T = K * Q^T : A-frag = 32 lanes x consecutive 16B (conflict-free)
#pragma unroll
      for (int kc = 0; kc < 4; ++kc) {
        short8 kf = *(const short8*)((const char*)Ks + (2 * kc + hi) * 1024 +
                                     (half * 32 + lq) * 16);
        sacc = __builtin_amdgcn_mfma_f32_32x32x16_bf16(kf, qf[kc], sacc, 0, 0, 0);
      }
      // softmax: clamp via med3 then exp2; masked rows hit -CLIP2 exactly
#pragma unroll
      for (int r = 0; r < 16; ++r) {
        float v = __builtin_amdgcn_fmed3f(sacc[r], -CLIP2, CLIP2);
        float p = exp2f(v);
        sacc[r] = p;
        den += p;
      }
      // pack pairs (reg 2i, 2i+1): wds[i] holds P for A-frag word i directly
      unsigned int wds[8];
#pragma unroll
      for (int i = 0; i < 8; ++i) wds[i] = pack_rnd(sacc[i * 2], sacc[i * 2 + 1]);
      // PV: A-frag for kt = wds[4kt..4kt+3]; V B-frag conflict-free
#pragma unroll
      for (int kt = 0; kt < 2; ++kt) {
        union { unsigned int u[4]; short8 s; } pa;
        pa.u[0] = wds[kt * 4 + 0];
        pa.u[1] = wds[kt * 4 + 1];
        pa.u[2] = wds[kt * 4 + 2];
        pa.u[3] = wds[kt * 4 + 3];
#pragma unroll
        for (int dt = 0; dt < 2; ++dt) {
          short8 vf = *(const short8*)((const char*)Vt +
              (4 * half + 2 * kt + hi) * 1024 + (dt * 32 + lq) * 16);
          oacc[dt] = __builtin_amdgcn_mfma_f32_32x32x16_bf16(pa.s, vf, oacc[dt], 0, 0, 0);
        }
      }
    }
  }

  // denominator: lanes l and l^32 hold disjoint j-sums for the same q
  den += __shfl_xor(den, 32);
  if (l < 32) denP[(((size_t)js * 64 + bh) * 1024) + q0 + l] = den;

  // numerator partials: q from reg index (PV C-layout), d from lane
#pragma unroll
  for (int dt = 0; dt < 2; ++dt)
#pragma unroll
    for (int r = 0; r < 16; ++r) {
      int q = q0 + (r & 3) + 8 * (r >> 2) + 4 * hi;
      int d = dt * 32 + lq;
      numP[((((size_t)js * 64 + bh) * 1024 + q) * 64) + d] = f2bf(oacc[dt][r]);
    }
}

// ---------------- combine j-split partials, divide, write Ob ----------------
__global__ __launch_bounds__(256) void attn_reduce_kernel(
    const unsigned short* __restrict__ numP, const float* __restrict__ denP,
    unsigned short* __restrict__ Ob) {
  int id = blockIdx.x * 256 + threadIdx.x;  // 0 .. 524287
  int d8 = id & 7;
  int q = (id >> 3) & 1023;
  int bh = id >> 13;
  int b = bh >> 4, h = bh & 15;
  float den = 0.f;
  float o[8] = {0.f, 0.f, 0.f, 0.f, 0.f, 0.f, 0.f, 0.f};
#pragma unroll
  for (int s = 0; s < 4; ++s) {
    const unsigned short* np =
        numP + ((((size_t)s * 64 + bh) * 1024 + q) * 64 + d8 * 8);
    u16x8 v = *(const u16x8*)np;
    den += denP[((size_t)s * 64 + bh) * 1024 + q];
#pragma unroll
    for (int e = 0; e < 8; ++e) o[e] += bf2f(v[e]);
  }
  float r = 1.0f / den;
  u16x8 outv;
#pragma unroll
  for (int e = 0; e < 8; ++e) outv[e] = f2bf(o[e] * r);
  *(u16x8*)&Ob[(((size_t)b * 1024 + q) * 1024) + h * 64 + d8 * 8] = outv;
}

// ---------------- launcher ----------------
extern "C" void kernel_launch(void* const* d_in, const int* in_sizes, int n_in,
                              void* d_out, int out_size, void* d_ws, size_t ws_size,
                              hipStream_t stream) {
  (void)in_sizes; (void)n_in; (void)out_size; (void)ws_size;
  const float* x    = (const float*)d_in[0];
  const float* ctx  = (const float*)d_in[1];
  const int*   mask = (const int*)d_in[2];
  const float* Wq   = (const float*)d_in[3];
  const float* Wkv  = (const float*)d_in[4];
  const float* Wo   = (const float*)d_in[5];
  const float* bo   = (const float*)d_in[6];
  float* out = (float*)d_out;

  char* ws = (char*)d_ws;
  const size_t MB = 1 << 20;
  // 0..40 MiB region is time-shared: {xb, cb} before attention; {numP, denP,
  // maskbias} after cb is consumed by the KV-GEMM (stream-ordered).
  unsigned short* numP = (unsigned short*)(ws + 0);        // 32 MiB : [4][64][1024][64] bf16
  float*          denP = (float*)(ws + 32 * MB);           // 1 MiB  : [4][64][1024] fp32
  float*          mbias= (float*)(ws + 33 * MB);           // 64 KiB : [4][4096] fp32
  unsigned short* xb   = (unsigned short*)(ws + 0);        // 8 MiB  : x bf16 [4096][1024]
  unsigned short* cb   = (unsigned short*)(ws + 8 * MB);   // 32 MiB : ctx bf16 [16384][1024]
  unsigned short* WqT  = (unsigned short*)(ws + 40 * MB);  // 2 MiB
  unsigned short* WkvT = (unsigned short*)(ws + 42 * MB);  // 4 MiB
  unsigned short* WoT  = (unsigned short*)(ws + 46 * MB);  // 2 MiB
  unsigned short* Qb   = (unsigned short*)(ws + 48 * MB);  // 8 MiB  : [bh][1024][64] (prescaled)
  unsigned short* K2   = (unsigned short*)(ws + 56 * MB);  // 32 MiB : [bh][d/8][4096][8]
  unsigned short* V2   = (unsigned short*)(ws + 88 * MB);  // 32 MiB : [bh][m/8][64][8]
  unsigned short* Ob   = (unsigned short*)(ws + 120 * MB); // 8 MiB  : [b][n][1024]

  cast_bf16_kernel<<<2048, 256, 0, stream>>>(x, xb, (4 * 1024 * 1024) / 8);
  cast_bf16_kernel<<<2048, 256, 0, stream>>>(ctx, cb, (16 * 1024 * 1024) / 8);
  transpose_cast_kernel<<<dim3(32, 32), 256, 0, stream>>>(Wq, WqT, 1024, 1024);
  transpose_cast_kernel<<<dim3(64, 32), 256, 0, stream>>>(Wkv, WkvT, 1024, 2048);
  transpose_cast_kernel<<<dim3(32, 32), 256, 0, stream>>>(Wo, WoT, 1024, 1024);

  gemm_bt_kernel<0><<<dim3(8, 32), 256, 0, stream>>>(xb, WqT, 4096, 1024, 1024,
                                                     Qb, (unsigned short*)nullptr,
                                                     (float*)nullptr, (const float*)nullptr);
  gemm_bt_kernel<1><<<dim3(16, 128), 256, 0, stream>>>(cb, WkvT, 16384, 2048, 1024,
                                                       K2, V2,
                                                       (float*)nullptr, (const float*)nullptr);
  // mbias overlaps the (now-dead) cb region; launched after the KV-GEMM reads cb
  mask_bias_kernel<<<64, 256, 0, stream>>>(mask, mbias, 4 * 4096);
  attn_kernel<<<2048, 256, 0, stream>>>(K2, V2, Qb, mbias, numP, denP);
  attn_reduce_kernel<<<2048, 256, 0, stream>>>(numP, denP, Ob);
  gemm_bt_kernel<2><<<dim3(8, 32), 256, 0, stream>>>(Ob, WoT, 4096, 1024, 1024,
                                                     (unsigned short*)nullptr, (unsigned short*)nullptr,
                                                     out, bo);
}

// Round 10
// 259.761 us; speedup vs baseline: 1.9839x; 1.0042x over previous
//
#include <hip/hip_runtime.h>
#include <hip/hip_bf16.h>

// Problem constants
// B=4, N=1024, M=4096, DQ=DC=1024, H=16, DH=64, INNER=1024, SCALE=0.125

typedef __attribute__((ext_vector_type(8))) short short8;          // 8 bf16 (MFMA A/B frag)
typedef __attribute__((ext_vector_type(8))) unsigned short u16x8;
typedef __attribute__((ext_vector_type(4))) float f32x4;
typedef __attribute__((ext_vector_type(16))) float f32x16;

static __device__ __forceinline__ void gload_lds16(const void* g, void* l) {
  __builtin_amdgcn_global_load_lds((const __attribute__((address_space(1))) void*)g,
                                   (__attribute__((address_space(3))) void*)l, 16, 0, 0);
}

static __device__ __forceinline__ unsigned short f2bf(float f) {
  __hip_bfloat16 h = __float2bfloat16(f);
  unsigned short u;
  __builtin_memcpy(&u, &h, 2);
  return u;
}

static __device__ __forceinline__ float bf2f(unsigned short u) {
  unsigned int x = (unsigned int)u << 16;
  float f;
  __builtin_memcpy(&f, &x, 4);
  return f;
}

// pack two positive floats to one u32 of 2 bf16 (round-half-up): 3 VALU ops.
static __device__ __forceinline__ unsigned int pack_rnd(float a, float b) {
  unsigned int ua, ub;
  __builtin_memcpy(&ua, &a, 4);
  __builtin_memcpy(&ub, &b, 4);
  return __builtin_amdgcn_perm(ua + 0x8000u, ub + 0x8000u, 0x03020706u);
}

// ---------------- cast fp32 -> bf16, 8 elems/thread ----------------
__global__ __launch_bounds__(256) void cast_bf16_kernel(const float* __restrict__ in,
                                                        unsigned short* __restrict__ out,
                                                        int n8) {
  int idx = blockIdx.x * 256 + threadIdx.x;
  int stride = gridDim.x * 256;
  for (int i = idx; i < n8; i += stride) {
    const float4* p = (const float4*)in + (size_t)i * 2;
    float4 a = p[0], b = p[1];
    u16x8 r;
    r[0] = f2bf(a.x); r[1] = f2bf(a.y); r[2] = f2bf(a.z); r[3] = f2bf(a.w);
    r[4] = f2bf(b.x); r[5] = f2bf(b.y); r[6] = f2bf(b.z); r[7] = f2bf(b.w);
    *((u16x8*)out + i) = r;
  }
}

// ---------------- mask -> fp32 additive bias (0 / -1e30) ----------------
__global__ __launch_bounds__(256) void mask_bias_kernel(const int* __restrict__ mask,
                                                        float* __restrict__ bias, int n) {
  int i = blockIdx.x * 256 + threadIdx.x;
  if (i < n) bias[i] = mask[i] ? 0.0f : -1e30f;
}

// ---------------- transpose + cast: W[K][N] fp32 -> Wt[N][K] bf16 ----------------
__global__ __launch_bounds__(256) void transpose_cast_kernel(const float* __restrict__ W,
                                                             unsigned short* __restrict__ Wt,
                                                             int K, int N) {
  __shared__ float tile[32][33];
  int n0 = blockIdx.x * 32, k0 = blockIdx.y * 32;
  int tx = threadIdx.x & 31, ty = threadIdx.x >> 5;
#pragma unroll
  for (int r = 0; r < 32; r += 8)
    tile[ty + r][tx] = W[(size_t)(k0 + ty + r) * N + n0 + tx];
  __syncthreads();
#pragma unroll
  for (int r = 0; r < 32; r += 8)
    Wt[(size_t)(n0 + ty + r) * K + k0 + tx] = f2bf(tile[tx][ty + r]);
}

// ---------------- GEMM: C[M,N] = A[M,K](bf16,row) * Bt[N,K](bf16,row)^T ----------------
// XCD-chunked block swizzle: same-XCD blocks share an A-panel (T1).
// EPI 0: write Q layout [bh][n][64] bf16, PRESCALED by 0.125*log2(e)
// EPI 1: cols<1024 -> K2[bh][d>>3][m][d&7]; cols>=1024 -> V2[bh][m>>3][d][m&7]
// EPI 2: write fp32 outF[row*1024+col] = acc + bias[col]
template <int EPI>
__global__ __launch_bounds__(256, 2) void gemm_bt_kernel(
    const unsigned short* __restrict__ A, const unsigned short* __restrict__ Bt,
    int M, int N, int K,
    unsigned short* __restrict__ out0, unsigned short* __restrict__ out1,
    float* __restrict__ outF, const float* __restrict__ bias) {
  __shared__ unsigned short As[128 * 64];
  __shared__ unsigned short Bs[128 * 64];
  const int tid = threadIdx.x;
  const int l = tid & 63;
  const int lq = l & 15, g = l >> 4;
  const int w = tid >> 6;
  const int wr = w >> 1, wc = w & 1;
  // XCD-chunked swizzle (nwg % 8 == 0 for all our grids)
  const int nwg = gridDim.x * gridDim.y;
  const int idl = blockIdx.y * gridDim.x + blockIdx.x;
  const int lin = (idl & 7) * (nwg >> 3) + (idl >> 3);
  const int m0 = (lin / gridDim.x) * 128, n0 = (lin % gridDim.x) * 128;

  f32x4 acc[4][4] = {};

  for (int k0 = 0; k0 < K; k0 += 64) {
    __syncthreads();
#pragma unroll
    for (int t = 0; t < 4; ++t) {
      int c = t * 256 + tid;
      int row = c >> 3, cb = c & 7;
      int srcoff = (cb * 16) ^ ((row & 7) << 4);
      char* la = (char*)As + t * 4096 + (tid & 192) * 16;  // wave-uniform base
      gload_lds16((const char*)(A + (size_t)(m0 + row) * K + k0) + srcoff, la);
      char* lb = (char*)Bs + t * 4096 + (tid & 192) * 16;
      gload_lds16((const char*)(Bt + (size_t)(n0 + row) * K + k0) + srcoff, lb);
    }
    __syncthreads();
#pragma unroll
    for (int ks = 0; ks < 2; ++ks) {
      short8 af[4], bfr[4];
#pragma unroll
      for (int mt = 0; mt < 4; ++mt) {
        int row = wr * 64 + mt * 16 + lq;
        af[mt] = *(const short8*)&As[row * 64 + ((ks * 32 + g * 8) ^ ((row & 7) << 3))];
      }
#pragma unroll
      for (int nt = 0; nt < 4; ++nt) {
        int row = wc * 64 + nt * 16 + lq;
        bfr[nt] = *(const short8*)&Bs[row * 64 + ((ks * 32 + g * 8) ^ ((row & 7) << 3))];
      }
#pragma unroll
      for (int mt = 0; mt < 4; ++mt)
#pragma unroll
        for (int nt = 0; nt < 4; ++nt)
          acc[mt][nt] =
              __builtin_amdgcn_mfma_f32_16x16x32_bf16(af[mt], bfr[nt], acc[mt][nt], 0, 0, 0);
    }
  }

#pragma unroll
  for (int mt = 0; mt < 4; ++mt) {
#pragma unroll
    for (int nt = 0; nt < 4; ++nt) {
      if (EPI == 1 && n0 >= 1024) {
        // V2[bh][m>>3][d][m&7]: 4 m-consecutive values packed per lane
        int colb = n0 - 1024 + wc * 64 + nt * 16 + lq;
        int h = colb >> 6, d = colb & 63;
        int rowb = m0 + wr * 64 + mt * 16 + g * 4;
        int b = rowb >> 12, mm = rowb & 4095;
        ushort4 pk;
        pk.x = f2bf(acc[mt][nt][0]);
        pk.y = f2bf(acc[mt][nt][1]);
        pk.z = f2bf(acc[mt][nt][2]);
        pk.w = f2bf(acc[mt][nt][3]);
        size_t off = (((size_t)(b * 16 + h) * 512 + (mm >> 3)) * 64 + d) * 8 + (mm & 7);
        *(ushort4*)&out1[off] = pk;
      } else {
#pragma unroll
        for (int r = 0; r < 4; ++r) {
          int row = m0 + wr * 64 + mt * 16 + g * 4 + r;
          int col = n0 + wc * 64 + nt * 16 + lq;
          float v = acc[mt][nt][r];
          if (EPI == 0) {
            int b = row >> 10, nq = row & 1023;
            int h = col >> 6, d = col & 63;
            // fold softmax scale (0.125 * log2 e) into Q
            out0[(((size_t)(b * 16 + h)) * 1024 + nq) * 64 + d] =
                f2bf(v * 0.18033688011112042f);
          } else if (EPI == 1) {
            // K2[bh][d>>3][m][d&7]
            int b = row >> 12, mm = row & 4095;
            int h = col >> 6, d = col & 63;
            size_t off = (((size_t)(b * 16 + h) * 8 + (d >> 3)) * 4096 + mm) * 8 + (d & 7);
            out0[off] = f2bf(v);
          } else {
            outF[(size_t)row * 1024 + col] = v + bias[col];
          }
        }
      }
    }
  }
}

// ---------------- fused attention (j-split, in-register P, KVBLK=128) ----------------
// Round-9 data path (conflict-free d-block-major LDS, sigma-permuted K,
// in-register P, zero-shuffle PV). NEW: KVBLK 64->128 (8 loop iterations,
// half the barrier drains, 2x staging batches) + s_setprio(1) around the
// MFMA clusters (T5). LDS 32 KB -> still 3 blocks/CU at (256,3); resident
// chunk set 12 x 256 KB = 3 MB < 4 MB L2.
__global__ __launch_bounds__(256, 3) void attn_kernel(
    const unsigned short* __restrict__ K2, const unsigned short* __restrict__ V2,
    const unsigned short* __restrict__ Q, const float* __restrict__ maskb,
    unsigned short* __restrict__ numP, float* __restrict__ denP) {
  __shared__ unsigned short Ks[8 * 128 * 8];  // [db][jj (sigma'd)][8 d-elems]
  __shared__ unsigned short Vt[16 * 64 * 8];  // [jb][d][8 j-elems]

  const int tid = threadIdx.x;
  const int l = tid & 63, w = tid >> 6;
  const int lq = l & 31;  // q within the wave's 32-row block / row index
  const int hi = l >> 5;  // lane half

  // XCD-affine decode: id&7 = XCD; 8 consecutive same-XCD blocks share (bh,js)
  const int id = blockIdx.x;
  const int xcd = id & 7;
  const int kk = id >> 3;
  const int qi = kk & 7;
  const int pr = xcd * 32 + (kk >> 3);
  const int bh = pr & 63, js = pr >> 6;
  const int b = bh >> 4;
  const int q0 = qi * 128 + w * 32;

  const unsigned short* Qh = Q + (size_t)bh * 1024 * 64;
  const unsigned short* Kh = K2 + (size_t)bh * 8 * 4096 * 8;   // [db][m][8]
  const unsigned short* Vh = V2 + (size_t)bh * 512 * 64 * 8;   // [jb][d][8]
  const float* bb = maskb + b * 4096;

  const float CLIP2 = 7.213475204444817f;  // 5 * log2(e)

  // Q fragments (B-operand): lane holds Q[q0+lq][kc*16 + hi*8 + e], prescaled
  short8 qf[4];
#pragma unroll
  for (int kc = 0; kc < 4; ++kc)
    qf[kc] = *(const short8*)&Qh[(size_t)(q0 + lq) * 64 + kc * 16 + hi * 8];

  f32x16 oacc[2] = {};
  float den = 0.f;

  for (int jt = js * 8; jt < js * 8 + 8; ++jt) {
    const int j0 = jt * 128;
    __syncthreads();  // previous tile fully consumed
    // stage K: LDS slot (db, jj) <- K2[bh][db][j0 + sigma(jj)][0..8)
    // sigma swaps bits 2<->3 (involution), upper bits preserved.
#pragma unroll
    for (int t = 0; t < 4; ++t) {
      int c = t * 256 + tid;
      int db = c >> 7, jj = c & 127;
      int sig = (jj & ~12) | ((jj & 4) << 1) | ((jj & 8) >> 1);
      char* lk = (char*)Ks + t * 4096 + (tid & 192) * 16;
      gload_lds16((const char*)(Kh + ((size_t)db * 4096 + j0 + sig) * 8), lk);
    }
    // stage V: LDS slot (jb, d) <- V2[bh][j0/8 + jb][d][0..8) (fully coalesced)
#pragma unroll
    for (int t = 0; t < 4; ++t) {
      int c = t * 256 + tid;
      int jb = c >> 6, d = c & 63;
      char* lv = (char*)Vt + t * 4096 + (tid & 192) * 16;
      gload_lds16((const char*)(Vh + ((size_t)((j0 >> 3) + jb) * 64 + d) * 8), lv);
    }
    __syncthreads();

#pragma unroll
    for (int half = 0; half < 4; ++half) {
      // seed S accumulator with mask bias at sigma-mapped reg position:
      // reg r (bq=r>>2) -> j = (r&3) + 4*(bq&1) + 8*hi + 16*(bq>>1)
      f32x16 sacc;
#pragma unroll
      for (int bq = 0; bq < 4; ++bq) {
        f32x4 m4 = *(const f32x4*)&bb[j0 + half * 32 + ((bq & 1) << 2) + (hi << 3) +
                                      ((bq >> 1) << 4)];
        sacc[bq * 4 + 0] = m4[0];
        sacc[bq * 4 + 1] = m4[1];
        sacc[bq * 4 + 2] = m4[2];
        sacc[bq * 4 + 3] = m4[3];
      }
      // S^T = K * Q^T : A-frag = 32 lanes x consecutive 16B (conflict-free)
      __builtin_amdgcn_s_setprio(1);
#pragma unroll
      for (int kc = 0; kc < 4; ++kc) {
        short8 kf = *(const short8*)((const char*)Ks + (2 * kc + hi) * 2048 +
                                     (half * 32 + lq) * 16);
        sacc = __builtin_amdgcn_mfma_f32_32x32x16_bf16(kf, qf[kc], sacc, 0, 0, 0);
      }
      __builtin_amdgcn_s_setprio(0);
      // softmax: clamp via med3 then exp2; masked rows hit -CLIP2 exactly
#pragma unroll
      for (int r = 0; r < 16; ++r) {
        float v = __builtin_amdgcn_fmed3f(sacc[r], -CLIP2, CLIP2);
        float p = exp2f(v);
        sacc[r] = p;
        den += p;
      }
      // pack pairs (reg 2i, 2i+1): wds[i] holds P for A-frag word i directly
      unsigned int wds[8];
#pragma unroll
      for (int i = 0; i < 8; ++i) wds[i] = pack_rnd(sacc[i * 2], sacc[i * 2 + 1]);
      // PV: A-frag for kt = wds[4kt..4kt+3]; V B-frag conflict-free
      __builtin_amdgcn_s_setprio(1);
#pragma unroll
      for (int kt = 0; kt < 2; ++kt) {
        union { unsigned int u[4]; short8 s; } pa;
        pa.u[0] = wds[kt * 4 + 0];
        pa.u[1] = wds[kt * 4 + 1];
        pa.u[2] = wds[kt * 4 + 2];
        pa.u[3] = wds[kt * 4 + 3];
#pragma unroll
        for (int dt = 0; dt < 2; ++dt) {
          short8 vf = *(const short8*)((const char*)Vt +
              (4 * half + 2 * kt + hi) * 1024 + (dt * 32 + lq) * 16);
          oacc[dt] = __builtin_amdgcn_mfma_f32_32x32x16_bf16(pa.s, vf, oacc[dt], 0, 0, 0);
        }
      }
      __builtin_amdgcn_s_setprio(0);
    }
  }

  // denominator: lanes l and l^32 hold disjoint j-sums for the same q
  den += __shfl_xor(den, 32);
  if (l < 32) denP[(((size_t)js * 64 + bh) * 1024) + q0 + l] = den;

  // numerator partials: q from reg index (PV C-layout), d from lane
#pragma unroll
  for (int dt = 0; dt < 2; ++dt)
#pragma unroll
    for (int r = 0; r < 16; ++r) {
      int q = q0 + (r & 3) + 8 * (r >> 2) + 4 * hi;
      int d = dt * 32 + lq;
      numP[((((size_t)js * 64 + bh) * 1024 + q) * 64) + d] = f2bf(oacc[dt][r]);
    }
}

// ---------------- combine j-split partials, divide, write Ob ----------------
__global__ __launch_bounds__(256) void attn_reduce_kernel(
    const unsigned short* __restrict__ numP, const float* __restrict__ denP,
    unsigned short* __restrict__ Ob) {
  int id = blockIdx.x * 256 + threadIdx.x;  // 0 .. 524287
  int d8 = id & 7;
  int q = (id >> 3) & 1023;
  int bh = id >> 13;
  int b = bh >> 4, h = bh & 15;
  float den = 0.f;
  float o[8] = {0.f, 0.f, 0.f, 0.f, 0.f, 0.f, 0.f, 0.f};
#pragma unroll
  for (int s = 0; s < 4; ++s) {
    const unsigned short* np =
        numP + ((((size_t)s * 64 + bh) * 1024 + q) * 64 + d8 * 8);
    u16x8 v = *(const u16x8*)np;
    den += denP[((size_t)s * 64 + bh) * 1024 + q];
#pragma unroll
    for (int e = 0; e < 8; ++e) o[e] += bf2f(v[e]);
  }
  float r = 1.0f / den;
  u16x8 outv;
#pragma unroll
  for (int e = 0; e < 8; ++e) outv[e] = f2bf(o[e] * r);
  *(u16x8*)&Ob[(((size_t)b * 1024 + q) * 1024) + h * 64 + d8 * 8] = outv;
}

// ---------------- launcher ----------------
extern "C" void kernel_launch(void* const* d_in, const int* in_sizes, int n_in,
                              void* d_out, int out_size, void* d_ws, size_t ws_size,
                              hipStream_t stream) {
  (void)in_sizes; (void)n_in; (void)out_size; (void)ws_size;
  const float* x    = (const float*)d_in[0];
  const float* ctx  = (const float*)d_in[1];
  const int*   mask = (const int*)d_in[2];
  const float* Wq   = (const float*)d_in[3];
  const float* Wkv  = (const float*)d_in[4];
  const float* Wo   = (const float*)d_in[5];
  const float* bo   = (const float*)d_in[6];
  float* out = (float*)d_out;

  char* ws = (char*)d_ws;
  const size_t MB = 1 << 20;
  // 0..40 MiB region is time-shared: {xb, cb} before attention; {numP, denP,
  // maskbias} after cb is consumed by the KV-GEMM (stream-ordered).
  unsigned short* numP = (unsigned short*)(ws + 0);        // 32 MiB : [4][64][1024][64] bf16
  float*          denP = (float*)(ws + 32 * MB);           // 1 MiB  : [4][64][1024] fp32
  float*          mbias= (float*)(ws + 33 * MB);           // 64 KiB : [4][4096] fp32
  unsigned short* xb   = (unsigned short*)(ws + 0);        // 8 MiB  : x bf16 [4096][1024]
  unsigned short* cb   = (unsigned short*)(ws + 8 * MB);   // 32 MiB : ctx bf16 [16384][1024]
  unsigned short* WqT  = (unsigned short*)(ws + 40 * MB);  // 2 MiB
  unsigned short* WkvT = (unsigned short*)(ws + 42 * MB);  // 4 MiB
  unsigned short* WoT  = (unsigned short*)(ws + 46 * MB);  // 2 MiB
  unsigned short* Qb   = (unsigned short*)(ws + 48 * MB);  // 8 MiB  : [bh][1024][64] (prescaled)
  unsigned short* K2   = (unsigned short*)(ws + 56 * MB);  // 32 MiB : [bh][d/8][4096][8]
  unsigned short* V2   = (unsigned short*)(ws + 88 * MB);  // 32 MiB : [bh][m/8][64][8]
  unsigned short* Ob   = (unsigned short*)(ws + 120 * MB); // 8 MiB  : [b][n][1024]

  cast_bf16_kernel<<<2048, 256, 0, stream>>>(x, xb, (4 * 1024 * 1024) / 8);
  cast_bf16_kernel<<<2048, 256, 0, stream>>>(ctx, cb, (16 * 1024 * 1024) / 8);
  transpose_cast_kernel<<<dim3(32, 32), 256, 0, stream>>>(Wq, WqT, 1024, 1024);
  transpose_cast_kernel<<<dim3(64, 32), 256, 0, stream>>>(Wkv, WkvT, 1024, 2048);
  transpose_cast_kernel<<<dim3(32, 32), 256, 0, stream>>>(Wo, WoT, 1024, 1024);

  gemm_bt_kernel<0><<<dim3(8, 32), 256, 0, stream>>>(xb, WqT, 4096, 1024, 1024,
                                                     Qb, (unsigned short*)nullptr,
                                                     (float*)nullptr, (const float*)nullptr);
  gemm_bt_kernel<1><<<dim3(16, 128), 256, 0, stream>>>(cb, WkvT, 16384, 2048, 1024,
                                                       K2, V2,
                                                       (float*)nullptr, (const float*)nullptr);
  // mbias overlaps the (now-dead) cb region; launched after the KV-GEMM reads cb
  mask_bias_kernel<<<64, 256, 0, stream>>>(mask, mbias, 4 * 4096);
  attn_kernel<<<2048, 256, 0, stream>>>(K2, V2, Qb, mbias, numP, denP);
  attn_reduce_kernel<<<2048, 256, 0, stream>>>(numP, denP, Ob);
  gemm_bt_kernel<2><<<dim3(8, 32), 256, 0, stream>>>(Ob, WoT, 4096, 1024, 1024,
                                                     (unsigned short*)nullptr, (unsigned short*)nullptr,
                                                     out, bo);
}

// Round 11
// 243.179 us; speedup vs baseline: 2.1192x; 1.0682x over previous
//
#include <hip/hip_runtime.h>
#include <hip/hip_bf16.h>

// Problem constants
// B=4, N=1024, M=4096, DQ=DC=1024, H=16, DH=64, INNER=1024, SCALE=0.125

typedef __attribute__((ext_vector_type(8))) short short8;          // 8 bf16 (MFMA A/B frag)
typedef __attribute__((ext_vector_type(8))) unsigned short u16x8;
typedef __attribute__((ext_vector_type(4))) float f32x4;
typedef __attribute__((ext_vector_type(16))) float f32x16;

static __device__ __forceinline__ void gload_lds16(const void* g, void* l) {
  __builtin_amdgcn_global_load_lds((const __attribute__((address_space(1))) void*)g,
                                   (__attribute__((address_space(3))) void*)l, 16, 0, 0);
}

static __device__ __forceinline__ unsigned short f2bf(float f) {
  __hip_bfloat16 h = __float2bfloat16(f);
  unsigned short u;
  __builtin_memcpy(&u, &h, 2);
  return u;
}

static __device__ __forceinline__ float bf2f(unsigned short u) {
  unsigned int x = (unsigned int)u << 16;
  float f;
  __builtin_memcpy(&f, &x, 4);
  return f;
}

// pack two positive floats to one u32 of 2 bf16 (round-half-up): 3 VALU ops.
static __device__ __forceinline__ unsigned int pack_rnd(float a, float b) {
  unsigned int ua, ub;
  __builtin_memcpy(&ua, &a, 4);
  __builtin_memcpy(&ub, &b, 4);
  return __builtin_amdgcn_perm(ua + 0x8000u, ub + 0x8000u, 0x03020706u);
}

// ---------------- cast fp32 -> bf16, 8 elems/thread ----------------
__global__ __launch_bounds__(256) void cast_bf16_kernel(const float* __restrict__ in,
                                                        unsigned short* __restrict__ out,
                                                        int n8) {
  int idx = blockIdx.x * 256 + threadIdx.x;
  int stride = gridDim.x * 256;
  for (int i = idx; i < n8; i += stride) {
    const float4* p = (const float4*)in + (size_t)i * 2;
    float4 a = p[0], b = p[1];
    u16x8 r;
    r[0] = f2bf(a.x); r[1] = f2bf(a.y); r[2] = f2bf(a.z); r[3] = f2bf(a.w);
    r[4] = f2bf(b.x); r[5] = f2bf(b.y); r[6] = f2bf(b.z); r[7] = f2bf(b.w);
    *((u16x8*)out + i) = r;
  }
}

// ---------------- mask -> fp32 additive bias (0 / -1e30) ----------------
__global__ __launch_bounds__(256) void mask_bias_kernel(const int* __restrict__ mask,
                                                        float* __restrict__ bias, int n) {
  int i = blockIdx.x * 256 + threadIdx.x;
  if (i < n) bias[i] = mask[i] ? 0.0f : -1e30f;
}

// ---------------- transpose + cast: W[K][N] fp32 -> Wt[N][K] bf16 ----------------
__global__ __launch_bounds__(256) void transpose_cast_kernel(const float* __restrict__ W,
                                                             unsigned short* __restrict__ Wt,
                                                             int K, int N) {
  __shared__ float tile[32][33];
  int n0 = blockIdx.x * 32, k0 = blockIdx.y * 32;
  int tx = threadIdx.x & 31, ty = threadIdx.x >> 5;
#pragma unroll
  for (int r = 0; r < 32; r += 8)
    tile[ty + r][tx] = W[(size_t)(k0 + ty + r) * N + n0 + tx];
  __syncthreads();
#pragma unroll
  for (int r = 0; r < 32; r += 8)
    Wt[(size_t)(n0 + ty + r) * K + k0 + tx] = f2bf(tile[tx][ty + r]);
}

// ---------------- GEMM: C[M,N] = A[M,K](bf16,row) * Bt[N,K](bf16,row)^T ----------------
// XCD-chunked block swizzle: same-XCD blocks share an A-panel (T1).
// EPI 0: write Q layout [bh][n][64] bf16, PRESCALED by 0.125*log2(e)
// EPI 1: cols<1024 -> K2[bh][d>>3][m][d&7]; cols>=1024 -> V2[bh][m>>3][d][m&7]
// EPI 2: write fp32 outF[row*1024+col] = acc + bias[col]
template <int EPI>
__global__ __launch_bounds__(256, 2) void gemm_bt_kernel(
    const unsigned short* __restrict__ A, const unsigned short* __restrict__ Bt,
    int M, int N, int K,
    unsigned short* __restrict__ out0, unsigned short* __restrict__ out1,
    float* __restrict__ outF, const float* __restrict__ bias) {
  __shared__ unsigned short As[128 * 64];
  __shared__ unsigned short Bs[128 * 64];
  const int tid = threadIdx.x;
  const int l = tid & 63;
  const int lq = l & 15, g = l >> 4;
  const int w = tid >> 6;
  const int wr = w >> 1, wc = w & 1;
  // XCD-chunked swizzle (nwg % 8 == 0 for all our grids)
  const int nwg = gridDim.x * gridDim.y;
  const int idl = blockIdx.y * gridDim.x + blockIdx.x;
  const int lin = (idl & 7) * (nwg >> 3) + (idl >> 3);
  const int m0 = (lin / gridDim.x) * 128, n0 = (lin % gridDim.x) * 128;

  f32x4 acc[4][4] = {};

  for (int k0 = 0; k0 < K; k0 += 64) {
    __syncthreads();
#pragma unroll
    for (int t = 0; t < 4; ++t) {
      int c = t * 256 + tid;
      int row = c >> 3, cb = c & 7;
      int srcoff = (cb * 16) ^ ((row & 7) << 4);
      char* la = (char*)As + t * 4096 + (tid & 192) * 16;  // wave-uniform base
      gload_lds16((const char*)(A + (size_t)(m0 + row) * K + k0) + srcoff, la);
      char* lb = (char*)Bs + t * 4096 + (tid & 192) * 16;
      gload_lds16((const char*)(Bt + (size_t)(n0 + row) * K + k0) + srcoff, lb);
    }
    __syncthreads();
#pragma unroll
    for (int ks = 0; ks < 2; ++ks) {
      short8 af[4], bfr[4];
#pragma unroll
      for (int mt = 0; mt < 4; ++mt) {
        int row = wr * 64 + mt * 16 + lq;
        af[mt] = *(const short8*)&As[row * 64 + ((ks * 32 + g * 8) ^ ((row & 7) << 3))];
      }
#pragma unroll
      for (int nt = 0; nt < 4; ++nt) {
        int row = wc * 64 + nt * 16 + lq;
        bfr[nt] = *(const short8*)&Bs[row * 64 + ((ks * 32 + g * 8) ^ ((row & 7) << 3))];
      }
#pragma unroll
      for (int mt = 0; mt < 4; ++mt)
#pragma unroll
        for (int nt = 0; nt < 4; ++nt)
          acc[mt][nt] =
              __builtin_amdgcn_mfma_f32_16x16x32_bf16(af[mt], bfr[nt], acc[mt][nt], 0, 0, 0);
    }
  }

#pragma unroll
  for (int mt = 0; mt < 4; ++mt) {
#pragma unroll
    for (int nt = 0; nt < 4; ++nt) {
      if (EPI == 1 && n0 >= 1024) {
        // V2[bh][m>>3][d][m&7]: 4 m-consecutive values packed per lane
        int colb = n0 - 1024 + wc * 64 + nt * 16 + lq;
        int h = colb >> 6, d = colb & 63;
        int rowb = m0 + wr * 64 + mt * 16 + g * 4;
        int b = rowb >> 12, mm = rowb & 4095;
        ushort4 pk;
        pk.x = f2bf(acc[mt][nt][0]);
        pk.y = f2bf(acc[mt][nt][1]);
        pk.z = f2bf(acc[mt][nt][2]);
        pk.w = f2bf(acc[mt][nt][3]);
        size_t off = (((size_t)(b * 16 + h) * 512 + (mm >> 3)) * 64 + d) * 8 + (mm & 7);
        *(ushort4*)&out1[off] = pk;
      } else {
#pragma unroll
        for (int r = 0; r < 4; ++r) {
          int row = m0 + wr * 64 + mt * 16 + g * 4 + r;
          int col = n0 + wc * 64 + nt * 16 + lq;
          float v = acc[mt][nt][r];
          if (EPI == 0) {
            int b = row >> 10, nq = row & 1023;
            int h = col >> 6, d = col & 63;
            // fold softmax scale (0.125 * log2 e) into Q
            out0[(((size_t)(b * 16 + h)) * 1024 + nq) * 64 + d] =
                f2bf(v * 0.18033688011112042f);
          } else if (EPI == 1) {
            // K2[bh][d>>3][m][d&7]
            int b = row >> 12, mm = row & 4095;
            int h = col >> 6, d = col & 63;
            size_t off = (((size_t)(b * 16 + h) * 8 + (d >> 3)) * 4096 + mm) * 8 + (d & 7);
            out0[off] = f2bf(v);
          } else {
            outF[(size_t)row * 1024 + col] = v + bias[col];
          }
        }
      }
    }
  }
}

// ---------------- fused attention (j-split, in-register P, double-buffered) ----------------
// Round-9/10 data path (conflict-free d-block-major LDS, sigma-permuted K,
// in-register P, zero-shuffle PV, mask as MFMA C-seed, Q prescaled).
// NEW: KVBLK=64 DOUBLE-BUFFERED staging — STAGE(t+1) issued BEFORE compute(t),
// one barrier per tile. The compiler's vmcnt(0) drain at the barrier now hits
// loads that had the whole 2-half compute phase (~1500 cy) to land, instead of
// draining freshly-issued loads (round<=10 exposed the full VMEM latency).
// Same 32 KB LDS as round 10 (2 x (8K K + 8K V)), 3 blocks/CU, same resident
// chunk set (12 x 256 KB = 3 MB < 4 MB L2).
__global__ __launch_bounds__(256, 3) void attn_kernel(
    const unsigned short* __restrict__ K2, const unsigned short* __restrict__ V2,
    const unsigned short* __restrict__ Q, const float* __restrict__ maskb,
    unsigned short* __restrict__ numP, float* __restrict__ denP) {
  __shared__ unsigned short Ks[2][8 * 64 * 8];  // [buf][db][jj (sigma'd)][8 d-elems]
  __shared__ unsigned short Vt[2][8 * 64 * 8];  // [buf][jb][d][8 j-elems]

  const int tid = threadIdx.x;
  const int l = tid & 63, w = tid >> 6;
  const int lq = l & 31;  // q within the wave's 32-row block / row index
  const int hi = l >> 5;  // lane half

  // XCD-affine decode: id&7 = XCD; 8 consecutive same-XCD blocks share (bh,js)
  const int id = blockIdx.x;
  const int xcd = id & 7;
  const int kk = id >> 3;
  const int qi = kk & 7;
  const int pr = xcd * 32 + (kk >> 3);
  const int bh = pr & 63, js = pr >> 6;
  const int b = bh >> 4;
  const int q0 = qi * 128 + w * 32;

  const unsigned short* Qh = Q + (size_t)bh * 1024 * 64;
  const unsigned short* Kh = K2 + (size_t)bh * 8 * 4096 * 8;   // [db][m][8]
  const unsigned short* Vh = V2 + (size_t)bh * 512 * 64 * 8;   // [jb][d][8]
  const float* bb = maskb + b * 4096;

  const float CLIP2 = 7.213475204444817f;  // 5 * log2(e)

  // Q fragments (B-operand): lane holds Q[q0+lq][kc*16 + hi*8 + e], prescaled
  short8 qf[4];
#pragma unroll
  for (int kc = 0; kc < 4; ++kc)
    qf[kc] = *(const short8*)&Qh[(size_t)(q0 + lq) * 64 + kc * 16 + hi * 8];

  f32x16 oacc[2] = {};
  float den = 0.f;

  const int jbeg = js * 16, jend = jbeg + 16;  // 16 tiles of 64 j

  // staging: K slot (db,jj) <- K2[bh][db][j0 + sigma(jj)][0..8)
  //          V slot (jb,d)  <- V2[bh][j0/8 + jb][d][0..8)
#define STAGE_KV(bi_, j0_)                                                       \
  do {                                                                           \
    _Pragma("unroll") for (int t = 0; t < 2; ++t) {                              \
      int c = t * 256 + tid;                                                     \
      int db = c >> 6, jj = c & 63;                                              \
      int sig = (jj & 0x33) | ((jj & 4) << 1) | ((jj & 8) >> 1);                 \
      char* lk = (char*)(&Ks[bi_][0]) + t * 4096 + (tid & 192) * 16;             \
      gload_lds16((const char*)(Kh + ((size_t)db * 4096 + (j0_) + sig) * 8), lk);\
      char* lv = (char*)(&Vt[bi_][0]) + t * 4096 + (tid & 192) * 16;             \
      gload_lds16((const char*)(Vh + ((size_t)(((j0_) >> 3) + db) * 64 + jj) * 8), lv); \
    }                                                                            \
  } while (0)

  // prologue: stage first tile into buf 0
  STAGE_KV(0, jbeg * 64);
  __syncthreads();

  for (int jt = jbeg; jt < jend; ++jt) {
    const int j0 = jt * 64;
    const int cur = jt & 1;  // jbeg is even (js*16)
    // issue next tile's staging into the other buffer; lands during compute
    if (jt + 1 < jend) STAGE_KV(cur ^ 1, j0 + 64);

    const unsigned short* Kc = &Ks[cur][0];
    const unsigned short* Vc = &Vt[cur][0];

#pragma unroll
    for (int half = 0; half < 2; ++half) {
      // seed S accumulator with mask bias at sigma-mapped reg position:
      // reg r (bq=r>>2) -> j = (r&3) + 4*(bq&1) + 8*hi + 16*(bq>>1)
      f32x16 sacc;
#pragma unroll
      for (int bq = 0; bq < 4; ++bq) {
        f32x4 m4 = *(const f32x4*)&bb[j0 + half * 32 + ((bq & 1) << 2) + (hi << 3) +
                                      ((bq >> 1) << 4)];
        sacc[bq * 4 + 0] = m4[0];
        sacc[bq * 4 + 1] = m4[1];
        sacc[bq * 4 + 2] = m4[2];
        sacc[bq * 4 + 3] = m4[3];
      }
      // S^T = K * Q^T : A-frag = 32 lanes x consecutive 16B (conflict-free)
      __builtin_amdgcn_s_setprio(1);
#pragma unroll
      for (int kc = 0; kc < 4; ++kc) {
        short8 kf = *(const short8*)((const char*)Kc + (2 * kc + hi) * 1024 +
                                     (half * 32 + lq) * 16);
        sacc = __builtin_amdgcn_mfma_f32_32x32x16_bf16(kf, qf[kc], sacc, 0, 0, 0);
      }
      __builtin_amdgcn_s_setprio(0);
      // softmax: clamp via med3 then exp2; masked rows hit -CLIP2 exactly
#pragma unroll
      for (int r = 0; r < 16; ++r) {
        float v = __builtin_amdgcn_fmed3f(sacc[r], -CLIP2, CLIP2);
        float p = __builtin_amdgcn_exp2f(v);
        sacc[r] = p;
        den += p;
      }
      // pack pairs (reg 2i, 2i+1): wds[i] holds P for A-frag word i directly
      unsigned int wds[8];
#pragma unroll
      for (int i = 0; i < 8; ++i) wds[i] = pack_rnd(sacc[i * 2], sacc[i * 2 + 1]);
      // PV: A-frag for kt = wds[4kt..4kt+3]; V B-frag conflict-free
      __builtin_amdgcn_s_setprio(1);
#pragma unroll
      for (int kt = 0; kt < 2; ++kt) {
        union { unsigned int u[4]; short8 s; } pa;
        pa.u[0] = wds[kt * 4 + 0];
        pa.u[1] = wds[kt * 4 + 1];
        pa.u[2] = wds[kt * 4 + 2];
        pa.u[3] = wds[kt * 4 + 3];
#pragma unroll
        for (int dt = 0; dt < 2; ++dt) {
          short8 vf = *(const short8*)((const char*)Vc +
              (4 * half + 2 * kt + hi) * 1024 + (dt * 32 + lq) * 16);
          oacc[dt] = __builtin_amdgcn_mfma_f32_32x32x16_bf16(pa.s, vf, oacc[dt], 0, 0, 0);
        }
      }
      __builtin_amdgcn_s_setprio(0);
    }
    // barrier: drains (already-landed) next-tile staging; protects buf reuse
    __syncthreads();
  }
#undef STAGE_KV

  // denominator: lanes l and l^32 hold disjoint j-sums for the same q
  den += __shfl_xor(den, 32);
  if (l < 32) denP[(((size_t)js * 64 + bh) * 1024) + q0 + l] = den;

  // numerator partials: q from reg index (PV C-layout), d from lane
#pragma unroll
  for (int dt = 0; dt < 2; ++dt)
#pragma unroll
    for (int r = 0; r < 16; ++r) {
      int q = q0 + (r & 3) + 8 * (r >> 2) + 4 * hi;
      int d = dt * 32 + lq;
      numP[((((size_t)js * 64 + bh) * 1024 + q) * 64) + d] = f2bf(oacc[dt][r]);
    }
}

// ---------------- combine j-split partials, divide, write Ob ----------------
__global__ __launch_bounds__(256) void attn_reduce_kernel(
    const unsigned short* __restrict__ numP, const float* __restrict__ denP,
    unsigned short* __restrict__ Ob) {
  int id = blockIdx.x * 256 + threadIdx.x;  // 0 .. 524287
  int d8 = id & 7;
  int q = (id >> 3) & 1023;
  int bh = id >> 13;
  int b = bh >> 4, h = bh & 15;
  float den = 0.f;
  float o[8] = {0.f, 0.f, 0.f, 0.f, 0.f, 0.f, 0.f, 0.f};
#pragma unroll
  for (int s = 0; s < 4; ++s) {
    const unsigned short* np =
        numP + ((((size_t)s * 64 + bh) * 1024 + q) * 64 + d8 * 8);
    u16x8 v = *(const u16x8*)np;
    den += denP[((size_t)s * 64 + bh) * 1024 + q];
#pragma unroll
    for (int e = 0; e < 8; ++e) o[e] += bf2f(v[e]);
  }
  float r = 1.0f / den;
  u16x8 outv;
#pragma unroll
  for (int e = 0; e < 8; ++e) outv[e] = f2bf(o[e] * r);
  *(u16x8*)&Ob[(((size_t)b * 1024 + q) * 1024) + h * 64 + d8 * 8] = outv;
}

// ---------------- launcher ----------------
extern "C" void kernel_launch(void* const* d_in, const int* in_sizes, int n_in,
                              void* d_out, int out_size, void* d_ws, size_t ws_size,
                              hipStream_t stream) {
  (void)in_sizes; (void)n_in; (void)out_size; (void)ws_size;
  const float* x    = (const float*)d_in[0];
  const float* ctx  = (const float*)d_in[1];
  const int*   mask = (const int*)d_in[2];
  const float* Wq   = (const float*)d_in[3];
  const float* Wkv  = (const float*)d_in[4];
  const float* Wo   = (const float*)d_in[5];
  const float* bo   = (const float*)d_in[6];
  float* out = (float*)d_out;

  char* ws = (char*)d_ws;
  const size_t MB = 1 << 20;
  // 0..40 MiB region is time-shared: {xb, cb} before attention; {numP, denP,
  // maskbias} after cb is consumed by the KV-GEMM (stream-ordered).
  unsigned short* numP = (unsigned short*)(ws + 0);        // 32 MiB : [4][64][1024][64] bf16
  float*          denP = (float*)(ws + 32 * MB);           // 1 MiB  : [4][64][1024] fp32
  float*          mbias= (float*)(ws + 33 * MB);           // 64 KiB : [4][4096] fp32
  unsigned short* xb   = (unsigned short*)(ws + 0);        // 8 MiB  : x bf16 [4096][1024]
  unsigned short* cb   = (unsigned short*)(ws + 8 * MB);   // 32 MiB : ctx bf16 [16384][1024]
  unsigned short* WqT  = (unsigned short*)(ws + 40 * MB);  // 2 MiB
  unsigned short* WkvT = (unsigned short*)(ws + 42 * MB);  // 4 MiB
  unsigned short* WoT  = (unsigned short*)(ws + 46 * MB);  // 2 MiB
  unsigned short* Qb   = (unsigned short*)(ws + 48 * MB);  // 8 MiB  : [bh][1024][64] (prescaled)
  unsigned short* K2   = (unsigned short*)(ws + 56 * MB);  // 32 MiB : [bh][d/8][4096][8]
  unsigned short* V2   = (unsigned short*)(ws + 88 * MB);  // 32 MiB : [bh][m/8][64][8]
  unsigned short* Ob   = (unsigned short*)(ws + 120 * MB); // 8 MiB  : [b][n][1024]

  cast_bf16_kernel<<<2048, 256, 0, stream>>>(x, xb, (4 * 1024 * 1024) / 8);
  cast_bf16_kernel<<<2048, 256, 0, stream>>>(ctx, cb, (16 * 1024 * 1024) / 8);
  transpose_cast_kernel<<<dim3(32, 32), 256, 0, stream>>>(Wq, WqT, 1024, 1024);
  transpose_cast_kernel<<<dim3(64, 32), 256, 0, stream>>>(Wkv, WkvT, 1024, 2048);
  transpose_cast_kernel<<<dim3(32, 32), 256, 0, stream>>>(Wo, WoT, 1024, 1024);

  gemm_bt_kernel<0><<<dim3(8, 32), 256, 0, stream>>>(xb, WqT, 4096, 1024, 1024,
                                                     Qb, (unsigned short*)nullptr,
                                                     (float*)nullptr, (const float*)nullptr);
  gemm_bt_kernel<1><<<dim3(16, 128), 256, 0, stream>>>(cb, WkvT, 16384, 2048, 1024,
                                                       K2, V2,
                                                       (float*)nullptr, (const float*)nullptr);
  // mbias overlaps the (now-dead) cb region; launched after the KV-GEMM reads cb
  mask_bias_kernel<<<64, 256, 0, stream>>>(mask, mbias, 4 * 4096);
  attn_kernel<<<2048, 256, 0, stream>>>(K2, V2, Qb, mbias, numP, denP);
  attn_reduce_kernel<<<2048, 256, 0, stream>>>(numP, denP, Ob);
  gemm_bt_kernel<2><<<dim3(8, 32), 256, 0, stream>>>(Ob, WoT, 4096, 1024, 1024,
                                                     (unsigned short*)nullptr, (unsigned short*)nullptr,
                                                     out, bo);
}